// Round 6
// baseline (2065.109 us; speedup 1.0000x reference)
//
#include <hip/hip_runtime.h>
#include <math.h>

#define R_ 64
#define S_ 32
#define W_ 64
#define H_ 256
#define UF_ 20

typedef short bf16x8 __attribute__((ext_vector_type(8)));
typedef float f32x4  __attribute__((ext_vector_type(4)));

#define MFMA(a,b,c) __builtin_amdgcn_mfma_f32_16x16x32_bf16((a),(b),(c),0,0,0)

__device__ __forceinline__ float sigf(float x){ return 1.0f/(1.0f+__expf(-x)); }
__device__ __forceinline__ float tanhf_(float x){ float e=__expf(2.0f*x); return 1.0f-2.0f/(e+1.0f); }
__device__ __forceinline__ float seluf_(float x){
  const float sc=1.0507009873554805f, al=1.6732632423543772f;
  return x>0.0f ? sc*x : sc*al*(expf(x)-1.0f);
}
__device__ __forceinline__ short tobf(float f){
  unsigned u=__float_as_uint(f); u += 0x7fffu + ((u>>16)&1u); return (short)(u>>16);
}

// ---------------------------------------------------------------------------
// prep: fp32 embedding table -> bf16
// ---------------------------------------------------------------------------
__global__ void prep_embed(const float* __restrict__ e, short* __restrict__ o)
{
  int i = (blockIdx.x*256 + threadIdx.x)*4;
  float4 v = *(const float4*)&e[i];
  unsigned u0 = (unsigned short)tobf(v.x) | ((unsigned)(unsigned short)tobf(v.y)<<16);
  unsigned u1 = (unsigned short)tobf(v.z) | ((unsigned)(unsigned short)tobf(v.w)<<16);
  *(uint2*)&o[i] = make_uint2(u0,u1);
}

// ---------------------------------------------------------------------------
// Word-level weight swizzle: Bw[d][w 8][kt 16][f 6][lane 64][8 shorts]
// f = {R0,R1,Z0,Z1,N0,N1}; jt = f&1, gate = f>>1; j = 32w + jt*16 + (lane&15)
// kt<8 -> wih, kt>=8 -> whh (gate n: n_x from wih, n_h from whh)
// ---------------------------------------------------------------------------
__global__ void prep_word_w(const float* __restrict__ wih, const float* __restrict__ whh,
                            short* __restrict__ Bw)
{
  int idx = blockIdx.x*256 + threadIdx.x;            // 2*8*16*6*64 = 98304
  int lane = idx & 63;
  int rest = idx >> 6;
  int f  = rest % 6;  rest /= 6;
  int kt = rest % 16; rest /= 16;
  int w  = rest % 8;
  int d  = rest / 8;
  int gate = f >> 1;
  int j = 32*w + (f&1)*16 + (lane&15);
  int row = gate*256 + j;
  const float* W = (kt < 8 ? wih : whh) + (size_t)d*768*256;
  int k = (kt&7)*32 + (lane>>4)*8;
  short* dst = Bw + ((((size_t)(d*8 + w)*16 + kt)*6 + f)*64 + lane)*8;
#pragma unroll
  for (int jj=0;jj<8;jj++) dst[jj] = tobf(W[(size_t)row*256 + k + jj]);
}

// Recurrent-only swizzle (sent/rev): Bs[d][w 8][kt 8][f 6][64][8], all whh
__global__ void prep_rnn_w(const float* __restrict__ whh, short* __restrict__ Bs)
{
  int idx = blockIdx.x*256 + threadIdx.x;            // 2*8*8*6*64 = 49152
  int lane = idx & 63;
  int rest = idx >> 6;
  int f  = rest % 6; rest /= 6;
  int kt = rest % 8; rest /= 8;
  int w  = rest % 8;
  int d  = rest / 8;
  int j = 32*w + (f&1)*16 + (lane&15);
  int row = (f>>1)*256 + j;
  const float* W = whh + (size_t)d*768*256;
  int k = kt*32 + (lane>>4)*8;
  short* dst = Bs + ((((size_t)(d*8 + w)*8 + kt)*6 + f)*64 + lane)*8;
#pragma unroll
  for (int jj=0;jj<8;jj++) dst[jj] = tobf(W[(size_t)row*256 + k + jj]);
}

// Generic GEMM-B swizzle for sg_wih: Bg[ntile 96][kt 8][64][8]
__global__ void prep_gemm_w(const float* __restrict__ Wsrc, short* __restrict__ Bg)
{
  int idx = blockIdx.x*256 + threadIdx.x;            // 96*8*64 = 49152
  int lane = idx & 63;
  int rest = idx >> 6;
  int kt = rest % 8;
  int nt = rest / 8;
  int n = nt*16 + (lane&15);
  int k = kt*32 + (lane>>4)*8;
  short* dst = Bg + (((size_t)nt*8 + kt)*64 + lane)*8;
#pragma unroll
  for (int jj=0;jj<8;jj++) dst[jj] = tobf(Wsrc[(size_t)n*256 + k + jj]);
}

// ---------------------------------------------------------------------------
// Persistent word-level bi-GRU. 128 blocks; XCD-swizzled so each XCD serves
// one direction's 786 KB weight table (L2-resident). M=32/block, 512 thr,
// FORCED 2 waves/EU -> 256 VGPRs -> no spills. One barrier per step.
// kt=14,15 (h-part tail) held register-resident; kt=0..13 streamed from L2
// with a 1-deep software pipeline.
// ---------------------------------------------------------------------------
__global__ __attribute__((amdgpu_flat_work_group_size(512, 512),
                          amdgpu_waves_per_eu(2, 2)))
void word_gru(
    const int* __restrict__ toks, const short* __restrict__ embB,
    const short* __restrict__ Bw,
    const float* __restrict__ bih, const float* __restrict__ bhh,
    float* __restrict__ hfin)
{
  const int lo = blockIdx.x & 7;
  const int d  = lo >> 2;                          // XCD 0-3 -> dir0, 4-7 -> dir1
  const int g  = (blockIdx.x >> 3) * 4 + (lo & 3); // 0..63, each (d,g) once
  const int tid = threadIdx.x;
  const int w = tid >> 6, l = tid & 63;
  const int c = l & 15, q = l >> 4;

  __shared__ short hbf[2][32][264];       // double-buffered bf16 h
  __shared__ short ebuf[2][32][264];      // double-buffered bf16 emb rows
  __shared__ int   tokL[2048];

  for (int i = tid; i < 2048; i += 512)
    tokL[i] = toks[(size_t)g*2048 + i];   // block's 32x64 tokens contiguous
  for (int i = tid; i < 32*264; i += 512) ((short*)hbf[0])[i] = 0;

  float bR[2], bZ[2], bNX[2], bNH[2];
#pragma unroll
  for (int jt = 0; jt < 2; jt++) {
    int j = 32*w + jt*16 + c;
    bR[jt]  = bih[d*768 + j]       + bhh[d*768 + j];
    bZ[jt]  = bih[d*768 + 256 + j] + bhh[d*768 + 256 + j];
    bNX[jt] = bih[d*768 + 512 + j];
    bNH[jt] = bhh[d*768 + 512 + j];
  }
  float hst[2][2][4];                     // [mt][jt][rg]
#pragma unroll
  for (int a=0;a<2;a++)
#pragma unroll
  for (int b=0;b<2;b++)
#pragma unroll
  for (int r=0;r<4;r++) hst[a][b][r] = 0.0f;

  __syncthreads();

  const int erow = tid >> 4;              // 32 rows
  const int ech  = (tid & 15) * 16;       // 16 bf16 (32B) per thread
  uint4 ef0, ef1;
  {
    int tx = d ? 63 : 0;
    const uint4* s = (const uint4*)(embB + (size_t)tokL[erow*64 + tx]*256 + ech);
    ef0 = s[0]; ef1 = s[1];
  }

  const short* Bbase = Bw + (size_t)(d*8 + w)*16*6*512;   // per-wave table

  // register-resident B for kt=14,15 (48 VGPRs, reused 64 steps)
  bf16x8 Bres[2][6];
#pragma unroll
  for (int i = 0; i < 2; i++)
#pragma unroll
  for (int f = 0; f < 6; f++)
    Bres[i][f] = *(const bf16x8*)(Bbase + (14+i)*3072 + f*512 + l*8);

  for (int t = 0; t < 64; t++) {
    const int cur = t & 1;
    *(uint4*)&ebuf[cur][erow][ech]   = ef0;
    *(uint4*)&ebuf[cur][erow][ech+8] = ef1;
    __syncthreads();          // ebuf[cur] staged; hbf[cur] (prev epilogue) visible

    if (t < 63) {             // prefetch next step's embedding rows
      int tx = d ? (62 - t) : (t + 1);
      const uint4* s = (const uint4*)(embB + (size_t)tokL[erow*64 + tx]*256 + ech);
      ef0 = s[0]; ef1 = s[1];
    }

    f32x4 accR[2][2], accZ[2][2], accNX[2][2], accNH[2][2];
#pragma unroll
    for (int a=0;a<2;a++)
#pragma unroll
    for (int b=0;b<2;b++) { accR[a][b]=(f32x4)0.f; accZ[a][b]=(f32x4)0.f;
                            accNX[a][b]=(f32x4)0.f; accNH[a][b]=(f32x4)0.f; }

    const short* asE = &ebuf[cur][0][0];
    const short* asH = &hbf[cur][0][0];

    // streamed kt = 0..13, 1-deep pipelined
    bf16x8 bq[6], bn_[6];
#pragma unroll
    for (int f = 0; f < 6; f++) bq[f] = *(const bf16x8*)(Bbase + f*512 + l*8);
#pragma unroll
    for (int kt = 0; kt < 14; kt++) {
      const bool xph = (kt < 8);
      const short* asrc = xph ? asE : asH;
      const int ko = (kt & 7)*32 + q*8;
      bf16x8 a0 = *(const bf16x8*)&asrc[( 0+c)*264 + ko];
      bf16x8 a1 = *(const bf16x8*)&asrc[(16+c)*264 + ko];
      if (kt < 13) {
#pragma unroll
        for (int f = 0; f < 6; f++)
          bn_[f] = *(const bf16x8*)(Bbase + (kt+1)*3072 + f*512 + l*8);
      }
      accR[0][0]=MFMA(a0,bq[0],accR[0][0]); accR[0][1]=MFMA(a1,bq[0],accR[0][1]);
      accR[1][0]=MFMA(a0,bq[1],accR[1][0]); accR[1][1]=MFMA(a1,bq[1],accR[1][1]);
      accZ[0][0]=MFMA(a0,bq[2],accZ[0][0]); accZ[0][1]=MFMA(a1,bq[2],accZ[0][1]);
      accZ[1][0]=MFMA(a0,bq[3],accZ[1][0]); accZ[1][1]=MFMA(a1,bq[3],accZ[1][1]);
      if (xph) {
        accNX[0][0]=MFMA(a0,bq[4],accNX[0][0]); accNX[0][1]=MFMA(a1,bq[4],accNX[0][1]);
        accNX[1][0]=MFMA(a0,bq[5],accNX[1][0]); accNX[1][1]=MFMA(a1,bq[5],accNX[1][1]);
      } else {
        accNH[0][0]=MFMA(a0,bq[4],accNH[0][0]); accNH[0][1]=MFMA(a1,bq[4],accNH[0][1]);
        accNH[1][0]=MFMA(a0,bq[5],accNH[1][0]); accNH[1][1]=MFMA(a1,bq[5],accNH[1][1]);
      }
      if (kt < 13) {
#pragma unroll
        for (int f = 0; f < 6; f++) bq[f] = bn_[f];
      }
    }
    // resident kt = 14,15 (h-part)
#pragma unroll
    for (int i = 0; i < 2; i++) {
      const int ko = (6+i)*32 + q*8;
      bf16x8 a0 = *(const bf16x8*)&asH[( 0+c)*264 + ko];
      bf16x8 a1 = *(const bf16x8*)&asH[(16+c)*264 + ko];
      accR[0][0]=MFMA(a0,Bres[i][0],accR[0][0]); accR[0][1]=MFMA(a1,Bres[i][0],accR[0][1]);
      accR[1][0]=MFMA(a0,Bres[i][1],accR[1][0]); accR[1][1]=MFMA(a1,Bres[i][1],accR[1][1]);
      accZ[0][0]=MFMA(a0,Bres[i][2],accZ[0][0]); accZ[0][1]=MFMA(a1,Bres[i][2],accZ[0][1]);
      accZ[1][0]=MFMA(a0,Bres[i][3],accZ[1][0]); accZ[1][1]=MFMA(a1,Bres[i][3],accZ[1][1]);
      accNH[0][0]=MFMA(a0,Bres[i][4],accNH[0][0]); accNH[0][1]=MFMA(a1,Bres[i][4],accNH[0][1]);
      accNH[1][0]=MFMA(a0,Bres[i][5],accNH[1][0]); accNH[1][1]=MFMA(a1,Bres[i][5],accNH[1][1]);
    }

    // epilogue writes the OTHER hbf buffer: no second barrier needed
    const int nxt = 1 - cur;
#pragma unroll
    for (int mt = 0; mt < 2; mt++)
#pragma unroll
    for (int jt = 0; jt < 2; jt++)
#pragma unroll
    for (int rg = 0; rg < 4; rg++) {
      const float r = sigf(accR[jt][mt][rg] + bR[jt]);
      const float z = sigf(accZ[jt][mt][rg] + bZ[jt]);
      const float n = tanhf_(accNX[jt][mt][rg] + bNX[jt] + r*(accNH[jt][mt][rg] + bNH[jt]));
      float h = hst[mt][jt][rg];
      h = (1.0f - z)*n + z*h;
      hst[mt][jt][rg] = h;
      hbf[nxt][mt*16 + q*4 + rg][32*w + jt*16 + c] = tobf(h);
    }
  }
#pragma unroll
  for (int mt = 0; mt < 2; mt++)
#pragma unroll
  for (int jt = 0; jt < 2; jt++)
#pragma unroll
  for (int rg = 0; rg < 4; rg++) {
    const int m = mt*16 + q*4 + rg;
    const int j = 32*w + jt*16 + c;
    hfin[((size_t)d*2048 + g*32 + m)*256 + j] = hst[mt][jt][rg];
  }
}

// ---------------------------------------------------------------------------
// sent -> bf16 (sum of both directions)
// ---------------------------------------------------------------------------
__global__ void add2bf(const float* __restrict__ a, const float* __restrict__ b,
                       short* __restrict__ o)
{
  int i = (blockIdx.x*256 + threadIdx.x)*4;
  float4 x = *(const float4*)&a[i];
  float4 y = *(const float4*)&b[i];
  unsigned u0 = (unsigned short)tobf(x.x+y.x) | ((unsigned)(unsigned short)tobf(x.y+y.y)<<16);
  unsigned u1 = (unsigned short)tobf(x.z+y.z) | ((unsigned)(unsigned short)tobf(x.w+y.w)<<16);
  *(uint2*)&o[i] = make_uint2(u0,u1);
}

// ---------------------------------------------------------------------------
// MFMA GEMM: C[2048,1536] f32 = A[2048,256] bf16 @ Bg (prepped frags)
// block tile 64x128, 256 thr (4 waves), grid (32, 12)
// ---------------------------------------------------------------------------
__global__ __launch_bounds__(256) void gemm_gx(
    const short* __restrict__ A, const short* __restrict__ Bg, float* __restrict__ C)
{
  const int m0  = blockIdx.x * 64;
  const int n0t = blockIdx.y * 8;
  const int tid = threadIdx.x;
  const int w = tid >> 6, l = tid & 63;
  const int c = l & 15, q = l >> 4;
  __shared__ short As[64][264];
  {
    int row = tid >> 2, ch = (tid & 3) * 64;
    const uint4* s = (const uint4*)(A + (size_t)(m0+row)*256 + ch);
#pragma unroll
    for (int i = 0; i < 8; i++) *(uint4*)&As[row][ch + i*8] = s[i];
  }
  __syncthreads();
  f32x4 acc[4][2];
#pragma unroll
  for (int a=0;a<4;a++) { acc[a][0]=(f32x4)0.f; acc[a][1]=(f32x4)0.f; }
#pragma unroll
  for (int kt = 0; kt < 8; kt++) {
    const int ko = kt*32 + q*8;
    bf16x8 a0 = *(const bf16x8*)&As[ 0+c][ko];
    bf16x8 a1 = *(const bf16x8*)&As[16+c][ko];
    bf16x8 a2 = *(const bf16x8*)&As[32+c][ko];
    bf16x8 a3 = *(const bf16x8*)&As[48+c][ko];
    bf16x8 b0 = *(const bf16x8*)&Bg[(((size_t)(n0t + 2*w    )*8 + kt)*64 + l)*8];
    bf16x8 b1 = *(const bf16x8*)&Bg[(((size_t)(n0t + 2*w + 1)*8 + kt)*64 + l)*8];
    acc[0][0]=MFMA(a0,b0,acc[0][0]); acc[1][0]=MFMA(a1,b0,acc[1][0]);
    acc[2][0]=MFMA(a2,b0,acc[2][0]); acc[3][0]=MFMA(a3,b0,acc[3][0]);
    acc[0][1]=MFMA(a0,b1,acc[0][1]); acc[1][1]=MFMA(a1,b1,acc[1][1]);
    acc[2][1]=MFMA(a2,b1,acc[2][1]); acc[3][1]=MFMA(a3,b1,acc[3][1]);
  }
#pragma unroll
  for (int mt=0;mt<4;mt++)
#pragma unroll
  for (int nt=0;nt<2;nt++)
#pragma unroll
  for (int rg=0;rg<4;rg++)
    C[(size_t)(m0 + mt*16 + q*4 + rg)*1536 + (n0t + 2*w + nt)*16 + c] = acc[mt][nt][rg];
}

// ---------------------------------------------------------------------------
// Persistent sentence-level bi-GRU, whh REGISTER-RESIDENT (192 VGPRs),
// forced 2 waves/EU so the allocator actually has 256 regs.
// ---------------------------------------------------------------------------
__global__ __attribute__((amdgpu_flat_work_group_size(512, 512),
                          amdgpu_waves_per_eu(2, 2)))
void sent_gru(
    const float* __restrict__ gx, const short* __restrict__ Bs,
    const float* __restrict__ bih, const float* __restrict__ bhh,
    float* __restrict__ hs)
{
  const int d = blockIdx.x & 1;
  const int g = blockIdx.x >> 1;
  const int tid = threadIdx.x;
  const int w = tid >> 6, l = tid & 63;
  const int c = l & 15, q = l >> 4;

  __shared__ short hbf[16][264];
  for (int i = tid; i < 16*264; i += 512) ((short*)hbf)[i] = 0;

  bf16x8 Breg[8][6];
  {
    const short* Bbase = Bs + (size_t)(d*8 + w)*8*6*512 + l*8;
#pragma unroll
    for (int kt = 0; kt < 8; kt++)
#pragma unroll
    for (int f = 0; f < 6; f++)
      Breg[kt][f] = *(const bf16x8*)(Bbase + (kt*6 + f)*512);
  }

  float bR[2], bZ[2], bNX[2], bNH[2];
#pragma unroll
  for (int jt = 0; jt < 2; jt++) {
    int j = 32*w + jt*16 + c;
    bR[jt]  = bih[d*768 + j]       + bhh[d*768 + j];
    bZ[jt]  = bih[d*768 + 256 + j] + bhh[d*768 + 256 + j];
    bNX[jt] = bih[d*768 + 512 + j];
    bNH[jt] = bhh[d*768 + 512 + j];
  }
  float hst[2][4];
#pragma unroll
  for (int a=0;a<2;a++)
#pragma unroll
  for (int r=0;r<4;r++) hst[a][r] = 0.0f;
  __syncthreads();

  for (int t = 0; t < 32; t++) {
    const int s_eff = (d == 0) ? t : (31 - t);
    // issue gx loads BEFORE the MFMA loop so latency overlaps compute
    float gr[2][4], gz[2][4], gn[2][4];
#pragma unroll
    for (int jt = 0; jt < 2; jt++)
#pragma unroll
    for (int rg = 0; rg < 4; rg++) {
      const int m = q*4 + rg;
      const int j = 32*w + jt*16 + c;
      const size_t row = ((size_t)(g*16 + m)*32 + s_eff)*1536 + d*768;
      gr[jt][rg] = gx[row + j];
      gz[jt][rg] = gx[row + 256 + j];
      gn[jt][rg] = gx[row + 512 + j];
    }
    f32x4 accR[2], accZ[2], accNH[2];
#pragma unroll
    for (int a=0;a<2;a++) { accR[a]=(f32x4)0.f; accZ[a]=(f32x4)0.f; accNH[a]=(f32x4)0.f; }
#pragma unroll
    for (int kt = 0; kt < 8; kt++) {
      bf16x8 a0 = *(const bf16x8*)&hbf[c][kt*32 + q*8];
      accR[0]=MFMA(a0,Breg[kt][0],accR[0]);  accR[1]=MFMA(a0,Breg[kt][1],accR[1]);
      accZ[0]=MFMA(a0,Breg[kt][2],accZ[0]);  accZ[1]=MFMA(a0,Breg[kt][3],accZ[1]);
      accNH[0]=MFMA(a0,Breg[kt][4],accNH[0]); accNH[1]=MFMA(a0,Breg[kt][5],accNH[1]);
    }
    __syncthreads();
#pragma unroll
    for (int jt = 0; jt < 2; jt++)
#pragma unroll
    for (int rg = 0; rg < 4; rg++) {
      const float r = sigf(gr[jt][rg] + bR[jt] + accR[jt][rg]);
      const float z = sigf(gz[jt][rg] + bZ[jt] + accZ[jt][rg]);
      const float n = tanhf_(gn[jt][rg] + bNX[jt] + r*(accNH[jt][rg] + bNH[jt]));
      float h = hst[jt][rg];
      h = (1.0f - z)*n + z*h;
      hst[jt][rg] = h;
      hbf[q*4 + rg][32*w + jt*16 + c] = tobf(h);
    }
    __syncthreads();
  }
#pragma unroll
  for (int jt = 0; jt < 2; jt++)
#pragma unroll
  for (int rg = 0; rg < 4; rg++) {
    const int m = q*4 + rg;
    const int j = 32*w + jt*16 + c;
    hs[((size_t)d*64 + g*16 + m)*256 + j] = hst[jt][rg];
  }
}

// ---------------------------------------------------------------------------
// Review-level bi-GRU, batch 1, whh REGISTER-RESIDENT, 2 waves/EU forced.
// ---------------------------------------------------------------------------
__global__ __attribute__((amdgpu_flat_work_group_size(512, 512),
                          amdgpu_waves_per_eu(2, 2)))
void rev_gru(
    const float* __restrict__ gx, const short* __restrict__ Br,
    const float* __restrict__ bih, const float* __restrict__ bhh,
    float* __restrict__ doc)
{
  const int d = blockIdx.x;
  const int tid = threadIdx.x;
  const int w = tid >> 6, l = tid & 63;
  const int c = l & 15, q = l >> 4;

  __shared__ short hbf[16][264];
  for (int i = tid; i < 16*264; i += 512) ((short*)hbf)[i] = 0;

  bf16x8 Breg[8][6];
  {
    const short* Bbase = Br + (size_t)(d*8 + w)*8*6*512 + l*8;
#pragma unroll
    for (int kt = 0; kt < 8; kt++)
#pragma unroll
    for (int f = 0; f < 6; f++)
      Breg[kt][f] = *(const bf16x8*)(Bbase + (kt*6 + f)*512);
  }

  float bR[2], bZ[2], bNX[2], bNH[2];
#pragma unroll
  for (int jt = 0; jt < 2; jt++) {
    int j = 32*w + jt*16 + c;
    bR[jt]  = bih[d*768 + j]       + bhh[d*768 + j];
    bZ[jt]  = bih[d*768 + 256 + j] + bhh[d*768 + 256 + j];
    bNX[jt] = bih[d*768 + 512 + j];
    bNH[jt] = bhh[d*768 + 512 + j];
  }
  float hst[2][4];
#pragma unroll
  for (int a=0;a<2;a++)
#pragma unroll
  for (int r=0;r<4;r++) hst[a][r] = 0.0f;
  __syncthreads();

  for (int t = 0; t < 64; t++) {
    const int teff = (d == 0) ? t : (63 - t);
    float gr[2], gz[2], gn[2];
#pragma unroll
    for (int jt = 0; jt < 2; jt++) {
      const int j = 32*w + jt*16 + c;
      const size_t row = (size_t)teff*1536 + d*768;
      gr[jt] = gx[row + j]; gz[jt] = gx[row + 256 + j]; gn[jt] = gx[row + 512 + j];
    }
    f32x4 accR[2], accZ[2], accNH[2];
#pragma unroll
    for (int a=0;a<2;a++) { accR[a]=(f32x4)0.f; accZ[a]=(f32x4)0.f; accNH[a]=(f32x4)0.f; }
#pragma unroll
    for (int kt = 0; kt < 8; kt++) {
      bf16x8 a0 = *(const bf16x8*)&hbf[c][kt*32 + q*8];
      accR[0]=MFMA(a0,Breg[kt][0],accR[0]);  accR[1]=MFMA(a0,Breg[kt][1],accR[1]);
      accZ[0]=MFMA(a0,Breg[kt][2],accZ[0]);  accZ[1]=MFMA(a0,Breg[kt][3],accZ[1]);
      accNH[0]=MFMA(a0,Breg[kt][4],accNH[0]); accNH[1]=MFMA(a0,Breg[kt][5],accNH[1]);
    }
    __syncthreads();
#pragma unroll
    for (int jt = 0; jt < 2; jt++)
#pragma unroll
    for (int rg = 0; rg < 4; rg++) {
      const float r = sigf(gr[jt] + bR[jt] + accR[jt][rg]);
      const float z = sigf(gz[jt] + bZ[jt] + accZ[jt][rg]);
      const float n = tanhf_(gn[jt] + bNX[jt] + r*(accNH[jt][rg] + bNH[jt]));
      float h = hst[jt][rg];
      h = (1.0f - z)*n + z*h;
      hst[jt][rg] = h;
      hbf[q*4 + rg][32*w + jt*16 + c] = tobf(h);
    }
    __syncthreads();
  }
  if (q == 0) {
#pragma unroll
    for (int jt = 0; jt < 2; jt++)
      doc[d*256 + 32*w + jt*16 + c] = hst[jt][0];
  }
}

// ---------------------------------------------------------------------------
// fp32 GEMM, BM=16/BN=64: C[M,N] = A[M,K] @ B[N,K]^T (K ragged; for rev gx)
// ---------------------------------------------------------------------------
__global__ __launch_bounds__(256) void gemm_nt16(
    const float* __restrict__ A, const float* __restrict__ B, float* __restrict__ C,
    int M, int N, int K)
{
  const int m0 = blockIdx.x * 16;
  const int n0 = blockIdx.y * 64;
  const int tid = threadIdx.x;
  __shared__ float As[16][17];
  __shared__ float Bs[16][68];
  float acc[4] = {0,0,0,0};
  const int m  = tid >> 4, n4 = (tid & 15) * 4;
  const int bn = tid >> 2, bk = (tid & 3) * 4;
  for (int k0 = 0; k0 < K; k0 += 16) {
    const int ak = tid & 15;
    float av = (k0 + ak < K) ? A[(size_t)(m0+m)*K + k0 + ak] : 0.0f;
    float4 b4 = make_float4(0,0,0,0);
    if (k0 + bk < K) b4 = *(const float4*)&B[(size_t)(n0+bn)*K + k0 + bk];
    __syncthreads();
    As[ak][m] = av;
    Bs[bk+0][bn]=b4.x; Bs[bk+1][bn]=b4.y; Bs[bk+2][bn]=b4.z; Bs[bk+3][bn]=b4.w;
    __syncthreads();
#pragma unroll
    for (int k = 0; k < 16; k++) {
      const float a = As[k][m];
      const float4 bb = *(const float4*)&Bs[k][n4];
      acc[0]+=a*bb.x; acc[1]+=a*bb.y; acc[2]+=a*bb.z; acc[3]+=a*bb.w;
    }
  }
  *(float4*)&C[(size_t)(m0+m)*N + n0+n4] = make_float4(acc[0],acc[1],acc[2],acc[3]);
}

// ---------------------------------------------------------------------------
// Small glue kernels
// ---------------------------------------------------------------------------
__global__ void pbatch_k(const float* __restrict__ hs, const float* __restrict__ uf,
                         const float* __restrict__ ufw, float* __restrict__ pb)
{
  const int r = blockIdx.x, tid = threadIdx.x;
  __shared__ float nrm;
  if (tid == 0) {
    float s = 0.f;
    for (int i = 0; i < UF_; i++) { const float v = uf[r*UF_ + i]; s += v*v; }
    nrm = fmaxf(sqrtf(s), 1e-12f);
  }
  __syncthreads();
  if (tid < H_)  pb[r*276 + tid] = hs[r*H_ + tid] + hs[(size_t)R_*H_ + r*H_ + tid];
  if (tid < UF_) pb[r*276 + H_ + tid] = uf[r*UF_ + tid] / nrm * ufw[tid];
}

__global__ void rstars_k(const float* __restrict__ pb,
                         const float* __restrict__ w1, const float* __restrict__ b1,
                         const float* __restrict__ w2, const float* __restrict__ b2,
                         float* __restrict__ out)
{
  const int r = blockIdx.x, tid = threadIdx.x;   // 128 threads
  __shared__ float ps[276];
  __shared__ float s1[128];
  for (int i = tid; i < 276; i += 128) ps[i] = pb[r*276 + i];
  __syncthreads();
  float a = b1[tid];
  for (int k = 0; k < 276; k++) a += ps[k] * w1[tid*276 + k];
  s1[tid] = seluf_(a);
  __syncthreads();
  if (tid == 0) {
    float s = b2[0];
    for (int k = 0; k < 128; k++) s += s1[k] * w2[k];
    out[9 + r] = s;
  }
}

__global__ void pstars_k(const float* __restrict__ doc2,
                         const float* __restrict__ w1, const float* __restrict__ b1,
                         const float* __restrict__ w2, const float* __restrict__ b2,
                         float* __restrict__ out)
{
  const int tid = threadIdx.x;   // 128 threads
  __shared__ float dc[256];
  __shared__ float s1[128];
  dc[tid]       = doc2[tid]       + doc2[256 + tid];
  dc[128 + tid] = doc2[128 + tid] + doc2[384 + tid];
  __syncthreads();
  float a = b1[tid];
  for (int k = 0; k < 256; k++) a += dc[k] * w1[tid*256 + k];
  s1[tid] = seluf_(a);
  __syncthreads();
  if (tid < 9) {
    float s = b2[tid];
    for (int k = 0; k < 128; k++) s += s1[k] * w2[tid*128 + k];
    out[tid] = s;
  }
}

// ---------------------------------------------------------------------------
extern "C" void kernel_launch(void* const* d_in, const int* in_sizes, int n_in,
                              void* d_out, int out_size, void* d_ws, size_t ws_size,
                              hipStream_t stream)
{
  const int*   toks   = (const int*)  d_in[0];
  const float* uf     = (const float*)d_in[3];
  const float* embed  = (const float*)d_in[4];
  const float* wg_wih = (const float*)d_in[5];
  const float* wg_whh = (const float*)d_in[6];
  const float* wg_bih = (const float*)d_in[7];
  const float* wg_bhh = (const float*)d_in[8];
  const float* sg_wih = (const float*)d_in[9];
  const float* sg_whh = (const float*)d_in[10];
  const float* sg_bih = (const float*)d_in[11];
  const float* sg_bhh = (const float*)d_in[12];
  const float* rg_wih = (const float*)d_in[13];
  const float* rg_whh = (const float*)d_in[14];
  const float* rg_bih = (const float*)d_in[15];
  const float* rg_bhh = (const float*)d_in[16];
  const float* rfc_w1 = (const float*)d_in[17];
  const float* rfc_b1 = (const float*)d_in[18];
  const float* rfc_w2 = (const float*)d_in[19];
  const float* rfc_b2 = (const float*)d_in[20];
  const float* pfc_w1 = (const float*)d_in[21];
  const float* pfc_b1 = (const float*)d_in[22];
  const float* pfc_w2 = (const float*)d_in[23];
  const float* pfc_b2 = (const float*)d_in[24];
  const float* uf_w   = (const float*)d_in[25];
  float* out = (float*)d_out;
  float* ws  = (float*)d_ws;
  (void)in_sizes; (void)n_in; (void)out_size; (void)ws_size;

  const size_t OFF_EMBB = 0;
  const size_t OFF_BW   = OFF_EMBB + 6400000;
  const size_t OFF_BS   = OFF_BW   + 393216;
  const size_t OFF_BR   = OFF_BS   + 196608;
  const size_t OFF_BG   = OFF_BR   + 196608;
  const size_t OFF_HF   = OFF_BG   + 196608;
  const size_t OFF_SB   = OFF_HF   + 1048576;
  const size_t OFF_GXS  = OFF_SB   + 262144;
  const size_t OFF_HS   = OFF_GXS  + 3145728;
  const size_t OFF_PB   = OFF_HS   + 32768;
  const size_t OFF_GXR  = OFF_PB   + 17664;
  const size_t OFF_DOC  = OFF_GXR  + 98304;

  short* embB = (short*)(ws + OFF_EMBB);
  short* Bw   = (short*)(ws + OFF_BW);
  short* Bs   = (short*)(ws + OFF_BS);
  short* Br   = (short*)(ws + OFF_BR);
  short* Bg   = (short*)(ws + OFF_BG);
  float* hfin = ws + OFF_HF;
  short* sentb= (short*)(ws + OFF_SB);
  float* gxs  = ws + OFF_GXS;
  float* hs   = ws + OFF_HS;
  float* pb   = ws + OFF_PB;
  float* gxr  = ws + OFF_GXR;
  float* doc  = ws + OFF_DOC;

  prep_embed<<<12500, 256, 0, stream>>>(embed, embB);
  prep_word_w<<<384, 256, 0, stream>>>(wg_wih, wg_whh, Bw);
  prep_rnn_w<<<192, 256, 0, stream>>>(sg_whh, Bs);
  prep_rnn_w<<<192, 256, 0, stream>>>(rg_whh, Br);
  prep_gemm_w<<<192, 256, 0, stream>>>(sg_wih, Bg);

  // word-level persistent bi-GRU: 128 blocks (M=32), XCD-partitioned dirs
  word_gru<<<128, 512, 0, stream>>>(toks, embB, Bw, wg_bih, wg_bhh, hfin);
  add2bf<<<512, 256, 0, stream>>>(hfin, hfin + (size_t)2048*256, sentb);

  // sentence level: MFMA gx GEMM + persistent bi-GRU (weights in regs)
  gemm_gx<<<dim3(32, 12), 256, 0, stream>>>(sentb, Bg, gxs);
  sent_gru<<<8, 512, 0, stream>>>(gxs, Bs, sg_bih, sg_bhh, hs);

  // p_batch + r_stars
  pbatch_k<<<R_, 256, 0, stream>>>(hs, uf, uf_w, pb);
  rstars_k<<<R_, 128, 0, stream>>>(pb, rfc_w1, rfc_b1, rfc_w2, rfc_b2, out);

  // review level: fp32 gx GEMM + persistent bi-GRU + p_stars
  gemm_nt16<<<dim3(4, 24), 256, 0, stream>>>(pb, rg_wih, gxr, 64, 1536, 276);
  rev_gru<<<2, 512, 0, stream>>>(gxr, Br, rg_bih, rg_bhh, doc);
  pstars_k<<<1, 128, 0, stream>>>(doc, pfc_w1, pfc_b1, pfc_w2, pfc_b2, out);
}

// Round 7
// 1803.426 us; speedup vs baseline: 1.1451x; 1.1451x over previous
//
#include <hip/hip_runtime.h>
#include <math.h>

#define R_ 64
#define S_ 32
#define W_ 64
#define H_ 256
#define UF_ 20

typedef short bf16x8 __attribute__((ext_vector_type(8)));
typedef float f32x4  __attribute__((ext_vector_type(4)));

#define MFMA(a,b,c) __builtin_amdgcn_mfma_f32_16x16x32_bf16((a),(b),(c),0,0,0)

__device__ __forceinline__ float sigf(float x){ return 1.0f/(1.0f+__expf(-x)); }
__device__ __forceinline__ float tanhf_(float x){ float e=__expf(2.0f*x); return 1.0f-2.0f/(e+1.0f); }
__device__ __forceinline__ float seluf_(float x){
  const float sc=1.0507009873554805f, al=1.6732632423543772f;
  return x>0.0f ? sc*x : sc*al*(expf(x)-1.0f);
}
__device__ __forceinline__ short tobf(float f){
  unsigned u=__float_as_uint(f); u += 0x7fffu + ((u>>16)&1u); return (short)(u>>16);
}

// ---------------------------------------------------------------------------
// prep: fp32 embedding table -> bf16
// ---------------------------------------------------------------------------
__global__ void prep_embed(const float* __restrict__ e, short* __restrict__ o)
{
  int i = (blockIdx.x*256 + threadIdx.x)*4;
  float4 v = *(const float4*)&e[i];
  unsigned u0 = (unsigned short)tobf(v.x) | ((unsigned)(unsigned short)tobf(v.y)<<16);
  unsigned u1 = (unsigned short)tobf(v.z) | ((unsigned)(unsigned short)tobf(v.w)<<16);
  *(uint2*)&o[i] = make_uint2(u0,u1);
}

// ---------------------------------------------------------------------------
// Word-level weight swizzle: Bw[d][w 8][kt 16][f 6][lane 64][8 shorts]
// f = {R0,R1,Z0,Z1,N0,N1}; jt = f&1, gate = f>>1; j = 32w + jt*16 + (lane&15)
// kt<8 -> wih, kt>=8 -> whh (gate n: n_x from wih, n_h from whh)
// ---------------------------------------------------------------------------
__global__ void prep_word_w(const float* __restrict__ wih, const float* __restrict__ whh,
                            short* __restrict__ Bw)
{
  int idx = blockIdx.x*256 + threadIdx.x;            // 2*8*16*6*64 = 98304
  int lane = idx & 63;
  int rest = idx >> 6;
  int f  = rest % 6;  rest /= 6;
  int kt = rest % 16; rest /= 16;
  int w  = rest % 8;
  int d  = rest / 8;
  int gate = f >> 1;
  int j = 32*w + (f&1)*16 + (lane&15);
  int row = gate*256 + j;
  const float* W = (kt < 8 ? wih : whh) + (size_t)d*768*256;
  int k = (kt&7)*32 + (lane>>4)*8;
  short* dst = Bw + ((((size_t)(d*8 + w)*16 + kt)*6 + f)*64 + lane)*8;
#pragma unroll
  for (int jj=0;jj<8;jj++) dst[jj] = tobf(W[(size_t)row*256 + k + jj]);
}

// Recurrent-only swizzle (sent/rev): Bs[d][w 8][kt 8][f 6][64][8], all whh
__global__ void prep_rnn_w(const float* __restrict__ whh, short* __restrict__ Bs)
{
  int idx = blockIdx.x*256 + threadIdx.x;            // 2*8*8*6*64 = 49152
  int lane = idx & 63;
  int rest = idx >> 6;
  int f  = rest % 6; rest /= 6;
  int kt = rest % 8; rest /= 8;
  int w  = rest % 8;
  int d  = rest / 8;
  int j = 32*w + (f&1)*16 + (lane&15);
  int row = (f>>1)*256 + j;
  const float* W = whh + (size_t)d*768*256;
  int k = kt*32 + (lane>>4)*8;
  short* dst = Bs + ((((size_t)(d*8 + w)*8 + kt)*6 + f)*64 + lane)*8;
#pragma unroll
  for (int jj=0;jj<8;jj++) dst[jj] = tobf(W[(size_t)row*256 + k + jj]);
}

// Generic GEMM-B swizzle (N=1536, K=256): Bg[ntile 96][kt 8][64][8]
__global__ void prep_gemm_w(const float* __restrict__ Wsrc, short* __restrict__ Bg)
{
  int idx = blockIdx.x*256 + threadIdx.x;            // 96*8*64 = 49152
  int lane = idx & 63;
  int rest = idx >> 6;
  int kt = rest % 8;
  int nt = rest / 8;
  int n = nt*16 + (lane&15);
  int k = kt*32 + (lane>>4)*8;
  short* dst = Bg + (((size_t)nt*8 + kt)*64 + lane)*8;
#pragma unroll
  for (int jj=0;jj<8;jj++) dst[jj] = tobf(Wsrc[(size_t)n*256 + k + jj]);
}

// ---------------------------------------------------------------------------
// MFMA GEMM: C[M,1536] f32 = A[M,256] bf16 @ Bg (prepped frags)
// block tile 64x128, 256 thr (4 waves), grid (M/64, 12)
// Used for: gxv (vocab x-gates, M=50048) and sentence gx (M=2048).
// ---------------------------------------------------------------------------
__global__ __launch_bounds__(256) void gemm_gx(
    const short* __restrict__ A, const short* __restrict__ Bg, float* __restrict__ C)
{
  const int m0  = blockIdx.x * 64;
  const int n0t = blockIdx.y * 8;
  const int tid = threadIdx.x;
  const int w = tid >> 6, l = tid & 63;
  const int c = l & 15, q = l >> 4;
  __shared__ short As[64][264];
  {
    int row = tid >> 2, ch = (tid & 3) * 64;
    const uint4* s = (const uint4*)(A + (size_t)(m0+row)*256 + ch);
#pragma unroll
    for (int i = 0; i < 8; i++) *(uint4*)&As[row][ch + i*8] = s[i];
  }
  __syncthreads();
  f32x4 acc[4][2];
#pragma unroll
  for (int a=0;a<4;a++) { acc[a][0]=(f32x4)0.f; acc[a][1]=(f32x4)0.f; }
#pragma unroll
  for (int kt = 0; kt < 8; kt++) {
    const int ko = kt*32 + q*8;
    bf16x8 a0 = *(const bf16x8*)&As[ 0+c][ko];
    bf16x8 a1 = *(const bf16x8*)&As[16+c][ko];
    bf16x8 a2 = *(const bf16x8*)&As[32+c][ko];
    bf16x8 a3 = *(const bf16x8*)&As[48+c][ko];
    bf16x8 b0 = *(const bf16x8*)&Bg[(((size_t)(n0t + 2*w    )*8 + kt)*64 + l)*8];
    bf16x8 b1 = *(const bf16x8*)&Bg[(((size_t)(n0t + 2*w + 1)*8 + kt)*64 + l)*8];
    acc[0][0]=MFMA(a0,b0,acc[0][0]); acc[1][0]=MFMA(a1,b0,acc[1][0]);
    acc[2][0]=MFMA(a2,b0,acc[2][0]); acc[3][0]=MFMA(a3,b0,acc[3][0]);
    acc[0][1]=MFMA(a0,b1,acc[0][1]); acc[1][1]=MFMA(a1,b1,acc[1][1]);
    acc[2][1]=MFMA(a2,b1,acc[2][1]); acc[3][1]=MFMA(a3,b1,acc[3][1]);
  }
#pragma unroll
  for (int mt=0;mt<4;mt++)
#pragma unroll
  for (int nt=0;nt<2;nt++)
#pragma unroll
  for (int rg=0;rg<4;rg++)
    C[(size_t)(m0 + mt*16 + q*4 + rg)*1536 + (n0t + 2*w + nt)*16 + c] = acc[mt][nt][rg];
}

// ---------------------------------------------------------------------------
// Word-level recurrence, gx precomputed per VOCAB row (gxv[50048][1536] f32).
// 256 blocks = 128 groups(16 sentences) x 2 dirs; 512 thr / 8 waves.
// whh fragments REGISTER-RESIDENT (192 VGPRs/lane); in-loop global traffic =
// only the per-step gx gather (16 rows x 3 KB -> LDS). One barrier per step.
// ---------------------------------------------------------------------------
__global__ __launch_bounds__(512, 2) void word_rec(
    const int* __restrict__ toks, const float* __restrict__ gxv,
    const short* __restrict__ Bw,
    const float* __restrict__ bih, const float* __restrict__ bhh,
    float* __restrict__ hfin)
{
  const int d = blockIdx.x & 1;
  const int g = blockIdx.x >> 1;          // sentences g*16 .. g*16+15
  const int tid = threadIdx.x;
  const int w = tid >> 6, l = tid & 63;
  const int c = l & 15, q = l >> 4;

  __shared__ float gbuf[2][16][772];      // x-gates for the step (768 + pad)
  __shared__ short hbf[2][16][264];       // double-buffered bf16 h
  __shared__ int   tokL[1024];

  for (int i = tid; i < 1024; i += 512) tokL[i] = toks[(size_t)g*1024 + i];
  for (int i = tid; i < 16*264; i += 512) ((short*)hbf[0])[i] = 0;

  float bR[2], bZ[2], bNX[2], bNH[2];
#pragma unroll
  for (int jt = 0; jt < 2; jt++) {
    int j = 32*w + jt*16 + c;
    bR[jt]  = bih[d*768 + j]       + bhh[d*768 + j];
    bZ[jt]  = bih[d*768 + 256 + j] + bhh[d*768 + 256 + j];
    bNX[jt] = bih[d*768 + 512 + j];
    bNH[jt] = bhh[d*768 + 512 + j];
  }
  float hst[2][4];
#pragma unroll
  for (int a=0;a<2;a++)
#pragma unroll
  for (int r=0;r<4;r++) hst[a][r] = 0.0f;

  // register-resident whh fragments: Bw kt 8..15 (h-part)
  bf16x8 Breg[8][6];
  {
    const short* Bbase = Bw + (size_t)(d*8 + w)*16*6*512 + l*8;
#pragma unroll
    for (int kt = 0; kt < 8; kt++)
#pragma unroll
    for (int f = 0; f < 6; f++)
      Breg[kt][f] = *(const bf16x8*)(Bbase + (8+kt)*3072 + f*512);
  }
  __syncthreads();

  const int grow = tid >> 5;              // 16 rows, 32 thr/row
  const int gcol = (tid & 31) * 4;        // float4 base, k-stride 128

  for (int t = 0; t < 64; t++) {
    const int cur = t & 1;
    {
      const int tx = d ? (63 - t) : t;
      const float* src = gxv + (size_t)tokL[grow*64 + tx]*1536 + d*768 + gcol;
      float* dst = &gbuf[cur][grow][gcol];
#pragma unroll
      for (int k = 0; k < 6; k++)
        *(float4*)(dst + k*128) = *(const float4*)(src + k*128);
    }
    __syncthreads();          // gbuf[cur] staged; hbf[cur] (prev epilogue) visible

    f32x4 accR[2], accZ[2], accNH[2];
#pragma unroll
    for (int a=0;a<2;a++) { accR[a]=(f32x4)0.f; accZ[a]=(f32x4)0.f; accNH[a]=(f32x4)0.f; }

#pragma unroll
    for (int kt = 0; kt < 8; kt++) {
      bf16x8 a0 = *(const bf16x8*)&hbf[cur][c][kt*32 + q*8];
      accR[0]=MFMA(a0,Breg[kt][0],accR[0]);  accR[1]=MFMA(a0,Breg[kt][1],accR[1]);
      accZ[0]=MFMA(a0,Breg[kt][2],accZ[0]);  accZ[1]=MFMA(a0,Breg[kt][3],accZ[1]);
      accNH[0]=MFMA(a0,Breg[kt][4],accNH[0]); accNH[1]=MFMA(a0,Breg[kt][5],accNH[1]);
    }

    const int nxt = 1 - cur;
#pragma unroll
    for (int jt = 0; jt < 2; jt++)
#pragma unroll
    for (int rg = 0; rg < 4; rg++) {
      const int m = q*4 + rg;
      const int j = 32*w + jt*16 + c;
      const float gr = gbuf[cur][m][j];
      const float gz = gbuf[cur][m][256 + j];
      const float gn = gbuf[cur][m][512 + j];
      const float r = sigf(gr + bR[jt] + accR[jt][rg]);
      const float z = sigf(gz + bZ[jt] + accZ[jt][rg]);
      const float n = tanhf_(gn + bNX[jt] + r*(accNH[jt][rg] + bNH[jt]));
      float h = hst[jt][rg];
      h = (1.0f - z)*n + z*h;
      hst[jt][rg] = h;
      hbf[nxt][m][j] = tobf(h);
    }
  }
#pragma unroll
  for (int jt = 0; jt < 2; jt++)
#pragma unroll
  for (int rg = 0; rg < 4; rg++) {
    const int m = q*4 + rg;
    const int j = 32*w + jt*16 + c;
    hfin[((size_t)d*2048 + g*16 + m)*256 + j] = hst[jt][rg];
  }
}

// ---------------------------------------------------------------------------
// FALLBACK word-level bi-GRU (streaming x+h weights) — used if ws too small
// for gxv. Identical to the round-6 kernel (known-correct).
// ---------------------------------------------------------------------------
__global__ __launch_bounds__(512, 2) void word_gru(
    const int* __restrict__ toks, const short* __restrict__ embB,
    const short* __restrict__ Bw,
    const float* __restrict__ bih, const float* __restrict__ bhh,
    float* __restrict__ hfin)
{
  const int d = blockIdx.x & 1;
  const int g = blockIdx.x >> 1;
  const int tid = threadIdx.x;
  const int w = tid >> 6, l = tid & 63;
  const int c = l & 15, q = l >> 4;

  __shared__ short hbf[2][16][264];
  __shared__ short ebuf[2][16][264];
  __shared__ int   tokL[1024];

  for (int i = tid; i < 1024; i += 512) tokL[i] = toks[(size_t)g*1024 + i];
  for (int i = tid; i < 16*264; i += 512) ((short*)hbf[0])[i] = 0;

  float bR[2], bZ[2], bNX[2], bNH[2];
#pragma unroll
  for (int jt = 0; jt < 2; jt++) {
    int j = 32*w + jt*16 + c;
    bR[jt]  = bih[d*768 + j]       + bhh[d*768 + j];
    bZ[jt]  = bih[d*768 + 256 + j] + bhh[d*768 + 256 + j];
    bNX[jt] = bih[d*768 + 512 + j];
    bNH[jt] = bhh[d*768 + 512 + j];
  }
  float hst[2][4];
#pragma unroll
  for (int a=0;a<2;a++)
#pragma unroll
  for (int r=0;r<4;r++) hst[a][r] = 0.0f;
  __syncthreads();

  const int erow = tid >> 5;
  const int ech  = (tid & 31) * 8;
  uint4 ef;
  {
    int tx = d ? 63 : 0;
    ef = *(const uint4*)(embB + (size_t)tokL[erow*64 + tx]*256 + ech);
  }
  const short* Bbase = Bw + (size_t)(d*8 + w)*16*6*512;

  for (int t = 0; t < 64; t++) {
    const int cur = t & 1;
    *(uint4*)&ebuf[cur][erow][ech] = ef;
    __syncthreads();
    if (t < 63) {
      int tx = d ? (62 - t) : (t + 1);
      ef = *(const uint4*)(embB + (size_t)tokL[erow*64 + tx]*256 + ech);
    }
    f32x4 accR[2], accZ[2], accNX[2], accNH[2];
#pragma unroll
    for (int a=0;a<2;a++) { accR[a]=(f32x4)0.f; accZ[a]=(f32x4)0.f;
                            accNX[a]=(f32x4)0.f; accNH[a]=(f32x4)0.f; }
    const short* asE = &ebuf[cur][0][0];
    const short* asH = &hbf[cur][0][0];
#pragma unroll
    for (int kt = 0; kt < 16; kt++) {
      const bool xph = (kt < 8);
      const short* asrc = xph ? asE : asH;
      const int ko = (kt & 7)*32 + q*8;
      bf16x8 a0 = *(const bf16x8*)&asrc[c*264 + ko];
      const short* bp = Bbase + kt*3072 + l*8;
      bf16x8 b0 = *(const bf16x8*)(bp +    0);
      bf16x8 b1 = *(const bf16x8*)(bp +  512);
      bf16x8 b2 = *(const bf16x8*)(bp + 1024);
      bf16x8 b3 = *(const bf16x8*)(bp + 1536);
      bf16x8 b4 = *(const bf16x8*)(bp + 2048);
      bf16x8 b5 = *(const bf16x8*)(bp + 2560);
      accR[0]=MFMA(a0,b0,accR[0]); accR[1]=MFMA(a0,b1,accR[1]);
      accZ[0]=MFMA(a0,b2,accZ[0]); accZ[1]=MFMA(a0,b3,accZ[1]);
      if (xph) { accNX[0]=MFMA(a0,b4,accNX[0]); accNX[1]=MFMA(a0,b5,accNX[1]); }
      else     { accNH[0]=MFMA(a0,b4,accNH[0]); accNH[1]=MFMA(a0,b5,accNH[1]); }
    }
    const int nxt = 1 - cur;
#pragma unroll
    for (int jt = 0; jt < 2; jt++)
#pragma unroll
    for (int rg = 0; rg < 4; rg++) {
      const float r = sigf(accR[jt][rg] + bR[jt]);
      const float z = sigf(accZ[jt][rg] + bZ[jt]);
      const float n = tanhf_(accNX[jt][rg] + bNX[jt] + r*(accNH[jt][rg] + bNH[jt]));
      float h = hst[jt][rg];
      h = (1.0f - z)*n + z*h;
      hst[jt][rg] = h;
      hbf[nxt][q*4 + rg][32*w + jt*16 + c] = tobf(h);
    }
  }
#pragma unroll
  for (int jt = 0; jt < 2; jt++)
#pragma unroll
  for (int rg = 0; rg < 4; rg++) {
    const int m = q*4 + rg;
    const int j = 32*w + jt*16 + c;
    hfin[((size_t)d*2048 + g*16 + m)*256 + j] = hst[jt][rg];
  }
}

// ---------------------------------------------------------------------------
// sent -> bf16 (sum of both directions)
// ---------------------------------------------------------------------------
__global__ void add2bf(const float* __restrict__ a, const float* __restrict__ b,
                       short* __restrict__ o)
{
  int i = (blockIdx.x*256 + threadIdx.x)*4;
  float4 x = *(const float4*)&a[i];
  float4 y = *(const float4*)&b[i];
  unsigned u0 = (unsigned short)tobf(x.x+y.x) | ((unsigned)(unsigned short)tobf(x.y+y.y)<<16);
  unsigned u1 = (unsigned short)tobf(x.z+y.z) | ((unsigned)(unsigned short)tobf(x.w+y.w)<<16);
  *(uint2*)&o[i] = make_uint2(u0,u1);
}

// ---------------------------------------------------------------------------
// Persistent sentence-level bi-GRU, whh REGISTER-RESIDENT.
// ---------------------------------------------------------------------------
__global__ __launch_bounds__(512, 2) void sent_gru(
    const float* __restrict__ gx, const short* __restrict__ Bs,
    const float* __restrict__ bih, const float* __restrict__ bhh,
    float* __restrict__ hs)
{
  const int d = blockIdx.x & 1;
  const int g = blockIdx.x >> 1;
  const int tid = threadIdx.x;
  const int w = tid >> 6, l = tid & 63;
  const int c = l & 15, q = l >> 4;

  __shared__ short hbf[16][264];
  for (int i = tid; i < 16*264; i += 512) ((short*)hbf)[i] = 0;

  bf16x8 Breg[8][6];
  {
    const short* Bbase = Bs + (size_t)(d*8 + w)*8*6*512 + l*8;
#pragma unroll
    for (int kt = 0; kt < 8; kt++)
#pragma unroll
    for (int f = 0; f < 6; f++)
      Breg[kt][f] = *(const bf16x8*)(Bbase + (kt*6 + f)*512);
  }

  float bR[2], bZ[2], bNX[2], bNH[2];
#pragma unroll
  for (int jt = 0; jt < 2; jt++) {
    int j = 32*w + jt*16 + c;
    bR[jt]  = bih[d*768 + j]       + bhh[d*768 + j];
    bZ[jt]  = bih[d*768 + 256 + j] + bhh[d*768 + 256 + j];
    bNX[jt] = bih[d*768 + 512 + j];
    bNH[jt] = bhh[d*768 + 512 + j];
  }
  float hst[2][4];
#pragma unroll
  for (int a=0;a<2;a++)
#pragma unroll
  for (int r=0;r<4;r++) hst[a][r] = 0.0f;
  __syncthreads();

  for (int t = 0; t < 32; t++) {
    const int s_eff = (d == 0) ? t : (31 - t);
    float gr[2][4], gz[2][4], gn[2][4];
#pragma unroll
    for (int jt = 0; jt < 2; jt++)
#pragma unroll
    for (int rg = 0; rg < 4; rg++) {
      const int m = q*4 + rg;
      const int j = 32*w + jt*16 + c;
      const size_t row = ((size_t)(g*16 + m)*32 + s_eff)*1536 + d*768;
      gr[jt][rg] = gx[row + j];
      gz[jt][rg] = gx[row + 256 + j];
      gn[jt][rg] = gx[row + 512 + j];
    }
    f32x4 accR[2], accZ[2], accNH[2];
#pragma unroll
    for (int a=0;a<2;a++) { accR[a]=(f32x4)0.f; accZ[a]=(f32x4)0.f; accNH[a]=(f32x4)0.f; }
#pragma unroll
    for (int kt = 0; kt < 8; kt++) {
      bf16x8 a0 = *(const bf16x8*)&hbf[c][kt*32 + q*8];
      accR[0]=MFMA(a0,Breg[kt][0],accR[0]);  accR[1]=MFMA(a0,Breg[kt][1],accR[1]);
      accZ[0]=MFMA(a0,Breg[kt][2],accZ[0]);  accZ[1]=MFMA(a0,Breg[kt][3],accZ[1]);
      accNH[0]=MFMA(a0,Breg[kt][4],accNH[0]); accNH[1]=MFMA(a0,Breg[kt][5],accNH[1]);
    }
    __syncthreads();
#pragma unroll
    for (int jt = 0; jt < 2; jt++)
#pragma unroll
    for (int rg = 0; rg < 4; rg++) {
      const float r = sigf(gr[jt][rg] + bR[jt] + accR[jt][rg]);
      const float z = sigf(gz[jt][rg] + bZ[jt] + accZ[jt][rg]);
      const float n = tanhf_(gn[jt][rg] + bNX[jt] + r*(accNH[jt][rg] + bNH[jt]));
      float h = hst[jt][rg];
      h = (1.0f - z)*n + z*h;
      hst[jt][rg] = h;
      hbf[q*4 + rg][32*w + jt*16 + c] = tobf(h);
    }
    __syncthreads();
  }
#pragma unroll
  for (int jt = 0; jt < 2; jt++)
#pragma unroll
  for (int rg = 0; rg < 4; rg++) {
    const int m = q*4 + rg;
    const int j = 32*w + jt*16 + c;
    hs[((size_t)d*64 + g*16 + m)*256 + j] = hst[jt][rg];
  }
}

// ---------------------------------------------------------------------------
// Review-level bi-GRU, batch 1, whh REGISTER-RESIDENT. Grid 2 (dirs).
// ---------------------------------------------------------------------------
__global__ __launch_bounds__(512, 2) void rev_gru(
    const float* __restrict__ gx, const short* __restrict__ Br,
    const float* __restrict__ bih, const float* __restrict__ bhh,
    float* __restrict__ doc)
{
  const int d = blockIdx.x;
  const int tid = threadIdx.x;
  const int w = tid >> 6, l = tid & 63;
  const int c = l & 15, q = l >> 4;

  __shared__ short hbf[16][264];
  for (int i = tid; i < 16*264; i += 512) ((short*)hbf)[i] = 0;

  bf16x8 Breg[8][6];
  {
    const short* Bbase = Br + (size_t)(d*8 + w)*8*6*512 + l*8;
#pragma unroll
    for (int kt = 0; kt < 8; kt++)
#pragma unroll
    for (int f = 0; f < 6; f++)
      Breg[kt][f] = *(const bf16x8*)(Bbase + (kt*6 + f)*512);
  }

  float bR[2], bZ[2], bNX[2], bNH[2];
#pragma unroll
  for (int jt = 0; jt < 2; jt++) {
    int j = 32*w + jt*16 + c;
    bR[jt]  = bih[d*768 + j]       + bhh[d*768 + j];
    bZ[jt]  = bih[d*768 + 256 + j] + bhh[d*768 + 256 + j];
    bNX[jt] = bih[d*768 + 512 + j];
    bNH[jt] = bhh[d*768 + 512 + j];
  }
  float hst[2][4];
#pragma unroll
  for (int a=0;a<2;a++)
#pragma unroll
  for (int r=0;r<4;r++) hst[a][r] = 0.0f;
  __syncthreads();

  for (int t = 0; t < 64; t++) {
    const int teff = (d == 0) ? t : (63 - t);
    float gr[2], gz[2], gn[2];
#pragma unroll
    for (int jt = 0; jt < 2; jt++) {
      const int j = 32*w + jt*16 + c;
      const size_t row = (size_t)teff*1536 + d*768;
      gr[jt] = gx[row + j]; gz[jt] = gx[row + 256 + j]; gn[jt] = gx[row + 512 + j];
    }
    f32x4 accR[2], accZ[2], accNH[2];
#pragma unroll
    for (int a=0;a<2;a++) { accR[a]=(f32x4)0.f; accZ[a]=(f32x4)0.f; accNH[a]=(f32x4)0.f; }
#pragma unroll
    for (int kt = 0; kt < 8; kt++) {
      bf16x8 a0 = *(const bf16x8*)&hbf[c][kt*32 + q*8];
      accR[0]=MFMA(a0,Breg[kt][0],accR[0]);  accR[1]=MFMA(a0,Breg[kt][1],accR[1]);
      accZ[0]=MFMA(a0,Breg[kt][2],accZ[0]);  accZ[1]=MFMA(a0,Breg[kt][3],accZ[1]);
      accNH[0]=MFMA(a0,Breg[kt][4],accNH[0]); accNH[1]=MFMA(a0,Breg[kt][5],accNH[1]);
    }
    __syncthreads();
#pragma unroll
    for (int jt = 0; jt < 2; jt++)
#pragma unroll
    for (int rg = 0; rg < 4; rg++) {
      const float r = sigf(gr[jt] + bR[jt] + accR[jt][rg]);
      const float z = sigf(gz[jt] + bZ[jt] + accZ[jt][rg]);
      const float n = tanhf_(gn[jt] + bNX[jt] + r*(accNH[jt][rg] + bNH[jt]));
      float h = hst[jt][rg];
      h = (1.0f - z)*n + z*h;
      hst[jt][rg] = h;
      hbf[q*4 + rg][32*w + jt*16 + c] = tobf(h);
    }
    __syncthreads();
  }
  if (q == 0) {
#pragma unroll
    for (int jt = 0; jt < 2; jt++)
      doc[d*256 + 32*w + jt*16 + c] = hst[jt][0];
  }
}

// ---------------------------------------------------------------------------
// fp32 GEMM, BM=16/BN=64: C[M,N] = A[M,K] @ B[N,K]^T (K ragged; for rev gx)
// ---------------------------------------------------------------------------
__global__ __launch_bounds__(256) void gemm_nt16(
    const float* __restrict__ A, const float* __restrict__ B, float* __restrict__ C,
    int M, int N, int K)
{
  const int m0 = blockIdx.x * 16;
  const int n0 = blockIdx.y * 64;
  const int tid = threadIdx.x;
  __shared__ float As[16][17];
  __shared__ float Bs[16][68];
  float acc[4] = {0,0,0,0};
  const int m  = tid >> 4, n4 = (tid & 15) * 4;
  const int bn = tid >> 2, bk = (tid & 3) * 4;
  for (int k0 = 0; k0 < K; k0 += 16) {
    const int ak = tid & 15;
    float av = (k0 + ak < K) ? A[(size_t)(m0+m)*K + k0 + ak] : 0.0f;
    float4 b4 = make_float4(0,0,0,0);
    if (k0 + bk < K) b4 = *(const float4*)&B[(size_t)(n0+bn)*K + k0 + bk];
    __syncthreads();
    As[ak][m] = av;
    Bs[bk+0][bn]=b4.x; Bs[bk+1][bn]=b4.y; Bs[bk+2][bn]=b4.z; Bs[bk+3][bn]=b4.w;
    __syncthreads();
#pragma unroll
    for (int k = 0; k < 16; k++) {
      const float a = As[k][m];
      const float4 bb = *(const float4*)&Bs[k][n4];
      acc[0]+=a*bb.x; acc[1]+=a*bb.y; acc[2]+=a*bb.z; acc[3]+=a*bb.w;
    }
  }
  *(float4*)&C[(size_t)(m0+m)*N + n0+n4] = make_float4(acc[0],acc[1],acc[2],acc[3]);
}

// ---------------------------------------------------------------------------
// Small glue kernels
// ---------------------------------------------------------------------------
__global__ void pbatch_k(const float* __restrict__ hs, const float* __restrict__ uf,
                         const float* __restrict__ ufw, float* __restrict__ pb)
{
  const int r = blockIdx.x, tid = threadIdx.x;
  __shared__ float nrm;
  if (tid == 0) {
    float s = 0.f;
    for (int i = 0; i < UF_; i++) { const float v = uf[r*UF_ + i]; s += v*v; }
    nrm = fmaxf(sqrtf(s), 1e-12f);
  }
  __syncthreads();
  if (tid < H_)  pb[r*276 + tid] = hs[r*H_ + tid] + hs[(size_t)R_*H_ + r*H_ + tid];
  if (tid < UF_) pb[r*276 + H_ + tid] = uf[r*UF_ + tid] / nrm * ufw[tid];
}

__global__ void rstars_k(const float* __restrict__ pb,
                         const float* __restrict__ w1, const float* __restrict__ b1,
                         const float* __restrict__ w2, const float* __restrict__ b2,
                         float* __restrict__ out)
{
  const int r = blockIdx.x, tid = threadIdx.x;   // 128 threads
  __shared__ float ps[276];
  __shared__ float s1[128];
  for (int i = tid; i < 276; i += 128) ps[i] = pb[r*276 + i];
  __syncthreads();
  float a = b1[tid];
  for (int k = 0; k < 276; k++) a += ps[k] * w1[tid*276 + k];
  s1[tid] = seluf_(a);
  __syncthreads();
  if (tid == 0) {
    float s = b2[0];
    for (int k = 0; k < 128; k++) s += s1[k] * w2[k];
    out[9 + r] = s;
  }
}

__global__ void pstars_k(const float* __restrict__ doc2,
                         const float* __restrict__ w1, const float* __restrict__ b1,
                         const float* __restrict__ w2, const float* __restrict__ b2,
                         float* __restrict__ out)
{
  const int tid = threadIdx.x;   // 128 threads
  __shared__ float dc[256];
  __shared__ float s1[128];
  dc[tid]       = doc2[tid]       + doc2[256 + tid];
  dc[128 + tid] = doc2[128 + tid] + doc2[384 + tid];
  __syncthreads();
  float a = b1[tid];
  for (int k = 0; k < 256; k++) a += dc[k] * w1[tid*256 + k];
  s1[tid] = seluf_(a);
  __syncthreads();
  if (tid < 9) {
    float s = b2[tid];
    for (int k = 0; k < 128; k++) s += s1[k] * w2[tid*128 + k];
    out[tid] = s;
  }
}

// ---------------------------------------------------------------------------
extern "C" void kernel_launch(void* const* d_in, const int* in_sizes, int n_in,
                              void* d_out, int out_size, void* d_ws, size_t ws_size,
                              hipStream_t stream)
{
  const int*   toks   = (const int*)  d_in[0];
  const float* uf     = (const float*)d_in[3];
  const float* embed  = (const float*)d_in[4];
  const float* wg_wih = (const float*)d_in[5];
  const float* wg_whh = (const float*)d_in[6];
  const float* wg_bih = (const float*)d_in[7];
  const float* wg_bhh = (const float*)d_in[8];
  const float* sg_wih = (const float*)d_in[9];
  const float* sg_whh = (const float*)d_in[10];
  const float* sg_bih = (const float*)d_in[11];
  const float* sg_bhh = (const float*)d_in[12];
  const float* rg_wih = (const float*)d_in[13];
  const float* rg_whh = (const float*)d_in[14];
  const float* rg_bih = (const float*)d_in[15];
  const float* rg_bhh = (const float*)d_in[16];
  const float* rfc_w1 = (const float*)d_in[17];
  const float* rfc_b1 = (const float*)d_in[18];
  const float* rfc_w2 = (const float*)d_in[19];
  const float* rfc_b2 = (const float*)d_in[20];
  const float* pfc_w1 = (const float*)d_in[21];
  const float* pfc_b1 = (const float*)d_in[22];
  const float* pfc_w2 = (const float*)d_in[23];
  const float* pfc_b2 = (const float*)d_in[24];
  const float* uf_w   = (const float*)d_in[25];
  float* out = (float*)d_out;
  float* ws  = (float*)d_ws;
  (void)in_sizes; (void)n_in; (void)out_size;

  // workspace layout (float offsets)
  const size_t OFF_EMBB = 0;                         // 6,400,000
  const size_t OFF_BW   = OFF_EMBB + 6400000;        // 393,216
  const size_t OFF_BS   = OFF_BW   + 393216;         // 196,608
  const size_t OFF_BR   = OFF_BS   + 196608;         // 196,608
  const size_t OFF_BG   = OFF_BR   + 196608;         // 196,608
  const size_t OFF_BGW  = OFF_BG   + 196608;         // 196,608
  const size_t OFF_HF   = OFF_BGW  + 196608;         // 1,048,576
  const size_t OFF_SB   = OFF_HF   + 1048576;        // 262,144
  const size_t OFF_GXS  = OFF_SB   + 262144;         // 3,145,728
  const size_t OFF_HS   = OFF_GXS  + 3145728;        // 32,768
  const size_t OFF_PB   = OFF_HS   + 32768;          // 17,664
  const size_t OFF_GXR  = OFF_PB   + 17664;          // 98,304
  const size_t OFF_DOC  = OFF_GXR  + 98304;          // 512
  const size_t OFF_GXV  = OFF_DOC  + 512;            // 76,873,728 (50048*1536 f32)
  const size_t TOT_BIG  = OFF_GXV  + (size_t)50048*1536;

  short* embB = (short*)(ws + OFF_EMBB);
  short* Bw   = (short*)(ws + OFF_BW);
  short* Bs   = (short*)(ws + OFF_BS);
  short* Br   = (short*)(ws + OFF_BR);
  short* Bg   = (short*)(ws + OFF_BG);
  short* Bgw  = (short*)(ws + OFF_BGW);
  float* hfin = ws + OFF_HF;
  short* sentb= (short*)(ws + OFF_SB);
  float* gxs  = ws + OFF_GXS;
  float* hs   = ws + OFF_HS;
  float* pb   = ws + OFF_PB;
  float* gxr  = ws + OFF_GXR;
  float* doc  = ws + OFF_DOC;
  float* gxv  = ws + OFF_GXV;

  const bool big = ws_size >= TOT_BIG * sizeof(float);

  prep_embed<<<12500, 256, 0, stream>>>(embed, embB);
  prep_word_w<<<384, 256, 0, stream>>>(wg_wih, wg_whh, Bw);
  prep_rnn_w<<<192, 256, 0, stream>>>(sg_whh, Bs);
  prep_rnn_w<<<192, 256, 0, stream>>>(rg_whh, Br);
  prep_gemm_w<<<192, 256, 0, stream>>>(sg_wih, Bg);

  if (big) {
    // vocab-level x-gate precompute, then weight-resident recurrence
    prep_gemm_w<<<192, 256, 0, stream>>>(wg_wih, Bgw);   // wg_wih flat [1536][256]
    gemm_gx<<<dim3(782, 12), 256, 0, stream>>>(embB, Bgw, gxv);
    word_rec<<<256, 512, 0, stream>>>(toks, gxv, Bw, wg_bih, wg_bhh, hfin);
  } else {
    word_gru<<<256, 512, 0, stream>>>(toks, embB, Bw, wg_bih, wg_bhh, hfin);
  }
  add2bf<<<512, 256, 0, stream>>>(hfin, hfin + (size_t)2048*256, sentb);

  // sentence level: MFMA gx GEMM + persistent bi-GRU (weights in regs)
  gemm_gx<<<dim3(32, 12), 256, 0, stream>>>(sentb, Bg, gxs);
  sent_gru<<<8, 512, 0, stream>>>(gxs, Bs, sg_bih, sg_bhh, hs);

  // p_batch + r_stars
  pbatch_k<<<R_, 256, 0, stream>>>(hs, uf, uf_w, pb);
  rstars_k<<<R_, 128, 0, stream>>>(pb, rfc_w1, rfc_b1, rfc_w2, rfc_b2, out);

  // review level: fp32 gx GEMM + persistent bi-GRU + p_stars
  gemm_nt16<<<dim3(4, 24), 256, 0, stream>>>(pb, rg_wih, gxr, 64, 1536, 276);
  rev_gru<<<2, 512, 0, stream>>>(gxr, Br, rg_bih, rg_bhh, doc);
  pstars_k<<<1, 128, 0, stream>>>(doc, pfc_w1, pfc_b1, pfc_w2, pfc_b2, out);
}

// Round 8
// 810.716 us; speedup vs baseline: 2.5473x; 2.2245x over previous
//
#include <hip/hip_runtime.h>
#include <math.h>

#define R_ 64
#define S_ 32
#define W_ 64
#define H_ 256
#define UF_ 20
#define TC 4        // time-chunk for path B

typedef short bf16x8 __attribute__((ext_vector_type(8)));
typedef float f32x4  __attribute__((ext_vector_type(4)));

#define MFMA(a,b,c) __builtin_amdgcn_mfma_f32_16x16x32_bf16((a),(b),(c),0,0,0)

__device__ __forceinline__ float sigf(float x){ return 1.0f/(1.0f+__expf(-x)); }
__device__ __forceinline__ float tanhf_(float x){ float e=__expf(2.0f*x); return 1.0f-2.0f/(e+1.0f); }
__device__ __forceinline__ float seluf_(float x){
  const float sc=1.0507009873554805f, al=1.6732632423543772f;
  return x>0.0f ? sc*x : sc*al*(expf(x)-1.0f);
}
__device__ __forceinline__ short tobf(float f){
  unsigned u=__float_as_uint(f); u += 0x7fffu + ((u>>16)&1u); return (short)(u>>16);
}
__device__ __forceinline__ float bf2f(short s){
  return __uint_as_float(((unsigned)(unsigned short)s) << 16);
}
__device__ __forceinline__ unsigned pk2(float a, float b){
  return (unsigned)(unsigned short)tobf(a) | ((unsigned)(unsigned short)tobf(b) << 16);
}

// ---------------------------------------------------------------------------
// Word-level weight swizzle: Bw[d][w 8][kt 16][f 6][lane 64][8 shorts]
// (only kt 8..15, the whh h-part, is consumed by gru_rec; kept full for simplicity)
// ---------------------------------------------------------------------------
__global__ void prep_word_w(const float* __restrict__ wih, const float* __restrict__ whh,
                            short* __restrict__ Bw)
{
  int idx = blockIdx.x*256 + threadIdx.x;            // 98304
  int lane = idx & 63;
  int rest = idx >> 6;
  int f  = rest % 6;  rest /= 6;
  int kt = rest % 16; rest /= 16;
  int w  = rest % 8;
  int d  = rest / 8;
  int gate = f >> 1;
  int j = 32*w + (f&1)*16 + (lane&15);
  int row = gate*256 + j;
  const float* W = (kt < 8 ? wih : whh) + (size_t)d*768*256;
  int k = (kt&7)*32 + (lane>>4)*8;
  short* dst = Bw + ((((size_t)(d*8 + w)*16 + kt)*6 + f)*64 + lane)*8;
#pragma unroll
  for (int jj=0;jj<8;jj++) dst[jj] = tobf(W[(size_t)row*256 + k + jj]);
}

// Recurrent-only swizzle (sent/rev): Bs[d][w 8][kt 8][f 6][64][8], all whh
__global__ void prep_rnn_w(const float* __restrict__ whh, short* __restrict__ Bs)
{
  int idx = blockIdx.x*256 + threadIdx.x;            // 49152
  int lane = idx & 63;
  int rest = idx >> 6;
  int f  = rest % 6; rest /= 6;
  int kt = rest % 8; rest /= 8;
  int w  = rest % 8;
  int d  = rest / 8;
  int j = 32*w + (f&1)*16 + (lane&15);
  int row = (f>>1)*256 + j;
  const float* W = whh + (size_t)d*768*256;
  int k = kt*32 + (lane>>4)*8;
  short* dst = Bs + ((((size_t)(d*8 + w)*8 + kt)*6 + f)*64 + lane)*8;
#pragma unroll
  for (int jj=0;jj<8;jj++) dst[jj] = tobf(W[(size_t)row*256 + k + jj]);
}

// Generic GEMM-B swizzle (N=1536, K=256): Bg[ntile 96][kt 8][64][8]
__global__ void prep_gemm_w(const float* __restrict__ Wsrc, short* __restrict__ Bg)
{
  int idx = blockIdx.x*256 + threadIdx.x;            // 49152
  int lane = idx & 63;
  int rest = idx >> 6;
  int kt = rest % 8;
  int nt = rest / 8;
  int n = nt*16 + (lane&15);
  int k = kt*32 + (lane>>4)*8;
  short* dst = Bg + (((size_t)nt*8 + kt)*64 + lane)*8;
#pragma unroll
  for (int jj=0;jj<8;jj++) dst[jj] = tobf(Wsrc[(size_t)n*256 + k + jj]);
}

// ---------------------------------------------------------------------------
// Unified MFMA gx GEMM, C bf16 = A[.,256] @ B^T. Tile 64x128, 256 thr.
// mode 0: A = bf16 contiguous rows (Ab)                      (sentence gx)
// mode 1: A = fp32 contiguous rows of Af, clamped to Mclamp  (vocab gxv)
// mode 2: A = fp32 rows of Af gathered via token window      (chunked gxt)
//         row rr -> s=rr/TC, i=rr%TC, word = z? 63-(t0+i) : t0+i
// B ntile base gets +z*48 in mode 2 (dir-split weight halves); C += z*Czoff.
// ---------------------------------------------------------------------------
__global__ __launch_bounds__(256) void gemm_gxu(
    const short* __restrict__ Ab, const float* __restrict__ Af,
    const int* __restrict__ toks, const short* __restrict__ Bg,
    short* __restrict__ C, long Czoff,
    int mode, int t0, int Mclamp, int Cstride)
{
  const int z  = blockIdx.z;
  const int m0 = blockIdx.x * 64;
  const int yt = blockIdx.y * 8;                    // C ntile base (dir-local)
  const int ntb = (mode == 2 ? z*48 : 0) + yt;      // B ntile base
  const int tid = threadIdx.x;
  const int w = tid >> 6, l = tid & 63;
  const int c = l & 15, q = l >> 4;
  __shared__ short As[64][264];
  {
    const int row = tid >> 2, c0 = (tid & 3) * 64;
    if (mode == 0) {
      const uint4* s = (const uint4*)(Ab + (size_t)(m0+row)*256 + c0);
#pragma unroll
      for (int i = 0; i < 8; i++) *(uint4*)&As[row][c0 + i*8] = s[i];
    } else {
      int r;
      if (mode == 1) {
        r = m0 + row; if (r >= Mclamp) r = Mclamp - 1;
      } else {
        const int rr = m0 + row;
        const int s_ = rr / TC, i_ = rr % TC;
        const int wd = z ? (63 - (t0 + i_)) : (t0 + i_);
        r = toks[s_*64 + wd];
      }
      const float* s = Af + (size_t)r*256 + c0;
#pragma unroll
      for (int i = 0; i < 8; i++) {
        float4 v0 = *(const float4*)(s + i*8);
        float4 v1 = *(const float4*)(s + i*8 + 4);
        uint4 u;
        u.x = pk2(v0.x, v0.y); u.y = pk2(v0.z, v0.w);
        u.z = pk2(v1.x, v1.y); u.w = pk2(v1.z, v1.w);
        *(uint4*)&As[row][c0 + i*8] = u;
      }
    }
  }
  __syncthreads();
  f32x4 acc[4][2];
#pragma unroll
  for (int a = 0; a < 4; a++) { acc[a][0] = (f32x4)0.f; acc[a][1] = (f32x4)0.f; }
#pragma unroll
  for (int kt = 0; kt < 8; kt++) {
    const int ko = kt*32 + q*8;
    bf16x8 a0 = *(const bf16x8*)&As[ 0+c][ko];
    bf16x8 a1 = *(const bf16x8*)&As[16+c][ko];
    bf16x8 a2 = *(const bf16x8*)&As[32+c][ko];
    bf16x8 a3 = *(const bf16x8*)&As[48+c][ko];
    bf16x8 b0 = *(const bf16x8*)&Bg[(((size_t)(ntb + 2*w    )*8 + kt)*64 + l)*8];
    bf16x8 b1 = *(const bf16x8*)&Bg[(((size_t)(ntb + 2*w + 1)*8 + kt)*64 + l)*8];
    acc[0][0]=MFMA(a0,b0,acc[0][0]); acc[1][0]=MFMA(a1,b0,acc[1][0]);
    acc[2][0]=MFMA(a2,b0,acc[2][0]); acc[3][0]=MFMA(a3,b0,acc[3][0]);
    acc[0][1]=MFMA(a0,b1,acc[0][1]); acc[1][1]=MFMA(a1,b1,acc[1][1]);
    acc[2][1]=MFMA(a2,b1,acc[2][1]); acc[3][1]=MFMA(a3,b1,acc[3][1]);
  }
  short* Cz = C + (size_t)z * Czoff;
#pragma unroll
  for (int mt = 0; mt < 4; mt++)
#pragma unroll
  for (int nt = 0; nt < 2; nt++)
#pragma unroll
  for (int rg = 0; rg < 4; rg++)
    Cz[(size_t)(m0 + mt*16 + q*4 + rg)*Cstride + (yt + 2*w + nt)*16 + c] =
        tobf(acc[mt][nt][rg]);
}

// ---------------------------------------------------------------------------
// Unified bi-GRU recurrence, whh fragments REGISTER-RESIDENT (192 VGPR/lane).
// Block = (dir, group of 16 rows); 512 thr / 8 waves; one barrier per step.
// gx staged LDS per step (bf16). State persisted in hstate (fp32) across
// launches (chunked word mode).
// mode 0: word, gx per VOCAB row (gxF=gxv, stride 1536, col +d*768)
// mode 1: word chunk, gx per instance row s*TC+(t-t0) in gxF/gxB (stride 768)
// mode 2: sentence, gx row = rev*nwords + s_eff in gxF (stride 1536, +d*768)
// ---------------------------------------------------------------------------
__global__ __launch_bounds__(512, 2) void gru_rec(
    const int* __restrict__ toks,
    const short* __restrict__ gxF, const short* __restrict__ gxB,
    const short* __restrict__ Bh, int wstride, int koff,
    const float* __restrict__ bih, const float* __restrict__ bhh,
    float* __restrict__ hstate, int NS,
    int t0, int nsteps, int mode, int nwords)
{
  const int d = blockIdx.x & 1;
  const int g = blockIdx.x >> 1;
  const int tid = threadIdx.x;
  const int w = tid >> 6, l = tid & 63;
  const int c = l & 15, q = l >> 4;

  __shared__ short gbuf[2][16][784];
  __shared__ short hbf[2][16][264];
  __shared__ int   tokL[1024];

  if (mode == 0)
    for (int i = tid; i < 1024; i += 512) tokL[i] = toks[(size_t)g*1024 + i];

  // register-resident whh fragments
  bf16x8 Breg[8][6];
  {
    const short* Bb = Bh + (size_t)(d*8 + w)*wstride + (size_t)koff*3072 + l*8;
#pragma unroll
    for (int kt = 0; kt < 8; kt++)
#pragma unroll
    for (int f = 0; f < 6; f++)
      Breg[kt][f] = *(const bf16x8*)(Bb + (kt*6 + f)*512);
  }

  float bR[2], bZ[2], bNX[2], bNH[2];
#pragma unroll
  for (int jt = 0; jt < 2; jt++) {
    int j = 32*w + jt*16 + c;
    bR[jt]  = bih[d*768 + j]       + bhh[d*768 + j];
    bZ[jt]  = bih[d*768 + 256 + j] + bhh[d*768 + 256 + j];
    bNX[jt] = bih[d*768 + 512 + j];
    bNH[jt] = bhh[d*768 + 512 + j];
  }

  float hst[2][4];
  const int cur0 = t0 & 1;
  if (t0 == 0) {
#pragma unroll
    for (int a = 0; a < 2; a++)
#pragma unroll
    for (int r = 0; r < 4; r++) hst[a][r] = 0.0f;
  } else {
#pragma unroll
    for (int jt = 0; jt < 2; jt++)
#pragma unroll
    for (int rg = 0; rg < 4; rg++)
      hst[jt][rg] = hstate[((size_t)d*NS + g*16 + q*4 + rg)*256 + 32*w + jt*16 + c];
  }
#pragma unroll
  for (int jt = 0; jt < 2; jt++)
#pragma unroll
  for (int rg = 0; rg < 4; rg++)
    hbf[cur0][q*4 + rg][32*w + jt*16 + c] = tobf(hst[jt][rg]);

  __syncthreads();   // tokL + hbf init visible

  const int grow = tid >> 5;            // 16 rows, 32 thr/row
  const int gcol = (tid & 31) * 24;     // 24 shorts (48B) per thread

  for (int t = t0; t < t0 + nsteps; t++) {
    const int cur = t & 1, nxt = 1 - cur;
    { // stage this step's gx rows into LDS
      const short* src;
      if (mode == 0) {
        const int tx = d ? (nwords - 1 - t) : t;
        src = gxF + (size_t)tokL[grow*64 + tx]*1536 + d*768 + gcol;
      } else if (mode == 1) {
        const int r = (g*16 + grow)*TC + (t - t0);
        src = (d ? gxB : gxF) + (size_t)r*768 + gcol;
      } else {
        const int se = d ? (nwords - 1 - t) : t;
        src = gxF + ((size_t)(g*16 + grow)*nwords + se)*1536 + d*768 + gcol;
      }
      const uint4* s4 = (const uint4*)src;
      uint4 v0 = s4[0], v1 = s4[1], v2 = s4[2];
      uint4* dst = (uint4*)&gbuf[cur][grow][gcol];
      dst[0] = v0; dst[1] = v1; dst[2] = v2;
    }
    __syncthreads();   // gbuf[cur] staged; prev epilogue's hbf[cur] visible

    f32x4 accR[2], accZ[2], accNH[2];
#pragma unroll
    for (int a = 0; a < 2; a++) { accR[a]=(f32x4)0.f; accZ[a]=(f32x4)0.f; accNH[a]=(f32x4)0.f; }
#pragma unroll
    for (int kt = 0; kt < 8; kt++) {
      bf16x8 a0 = *(const bf16x8*)&hbf[cur][c][kt*32 + q*8];
      accR[0]=MFMA(a0,Breg[kt][0],accR[0]);  accR[1]=MFMA(a0,Breg[kt][1],accR[1]);
      accZ[0]=MFMA(a0,Breg[kt][2],accZ[0]);  accZ[1]=MFMA(a0,Breg[kt][3],accZ[1]);
      accNH[0]=MFMA(a0,Breg[kt][4],accNH[0]); accNH[1]=MFMA(a0,Breg[kt][5],accNH[1]);
    }

#pragma unroll
    for (int jt = 0; jt < 2; jt++)
#pragma unroll
    for (int rg = 0; rg < 4; rg++) {
      const int m = q*4 + rg;
      const int j = 32*w + jt*16 + c;
      const float gr = bf2f(gbuf[cur][m][j]);
      const float gz = bf2f(gbuf[cur][m][256 + j]);
      const float gn = bf2f(gbuf[cur][m][512 + j]);
      const float r = sigf(gr + bR[jt] + accR[jt][rg]);
      const float z = sigf(gz + bZ[jt] + accZ[jt][rg]);
      const float n = tanhf_(gn + bNX[jt] + r*(accNH[jt][rg] + bNH[jt]));
      float h = hst[jt][rg];
      h = (1.0f - z)*n + z*h;
      hst[jt][rg] = h;
      hbf[nxt][m][j] = tobf(h);
    }
  }

#pragma unroll
  for (int jt = 0; jt < 2; jt++)
#pragma unroll
  for (int rg = 0; rg < 4; rg++)
    hstate[((size_t)d*NS + g*16 + q*4 + rg)*256 + 32*w + jt*16 + c] = hst[jt][rg];
}

// ---------------------------------------------------------------------------
// sent -> bf16 (sum of both directions)
// ---------------------------------------------------------------------------
__global__ void add2bf(const float* __restrict__ a, const float* __restrict__ b,
                       short* __restrict__ o)
{
  int i = (blockIdx.x*256 + threadIdx.x)*4;
  float4 x = *(const float4*)&a[i];
  float4 y = *(const float4*)&b[i];
  *(uint2*)&o[i] = make_uint2(pk2(x.x+y.x, x.y+y.y), pk2(x.z+y.z, x.w+y.w));
}

// ---------------------------------------------------------------------------
// Review-level bi-GRU, batch 1, whh REGISTER-RESIDENT. Grid 2 (dirs).
// ---------------------------------------------------------------------------
__global__ __launch_bounds__(512, 2) void rev_gru(
    const float* __restrict__ gx, const short* __restrict__ Br,
    const float* __restrict__ bih, const float* __restrict__ bhh,
    float* __restrict__ doc)
{
  const int d = blockIdx.x;
  const int tid = threadIdx.x;
  const int w = tid >> 6, l = tid & 63;
  const int c = l & 15, q = l >> 4;

  __shared__ short hbf[16][264];
  for (int i = tid; i < 16*264; i += 512) ((short*)hbf)[i] = 0;

  bf16x8 Breg[8][6];
  {
    const short* Bbase = Br + (size_t)(d*8 + w)*8*6*512 + l*8;
#pragma unroll
    for (int kt = 0; kt < 8; kt++)
#pragma unroll
    for (int f = 0; f < 6; f++)
      Breg[kt][f] = *(const bf16x8*)(Bbase + (kt*6 + f)*512);
  }

  float bR[2], bZ[2], bNX[2], bNH[2];
#pragma unroll
  for (int jt = 0; jt < 2; jt++) {
    int j = 32*w + jt*16 + c;
    bR[jt]  = bih[d*768 + j]       + bhh[d*768 + j];
    bZ[jt]  = bih[d*768 + 256 + j] + bhh[d*768 + 256 + j];
    bNX[jt] = bih[d*768 + 512 + j];
    bNH[jt] = bhh[d*768 + 512 + j];
  }
  float hst[2][4];
#pragma unroll
  for (int a=0;a<2;a++)
#pragma unroll
  for (int r=0;r<4;r++) hst[a][r] = 0.0f;
  __syncthreads();

  for (int t = 0; t < 64; t++) {
    const int teff = (d == 0) ? t : (63 - t);
    float gr[2], gz[2], gn[2];
#pragma unroll
    for (int jt = 0; jt < 2; jt++) {
      const int j = 32*w + jt*16 + c;
      const size_t row = (size_t)teff*1536 + d*768;
      gr[jt] = gx[row + j]; gz[jt] = gx[row + 256 + j]; gn[jt] = gx[row + 512 + j];
    }
    f32x4 accR[2], accZ[2], accNH[2];
#pragma unroll
    for (int a=0;a<2;a++) { accR[a]=(f32x4)0.f; accZ[a]=(f32x4)0.f; accNH[a]=(f32x4)0.f; }
#pragma unroll
    for (int kt = 0; kt < 8; kt++) {
      bf16x8 a0 = *(const bf16x8*)&hbf[c][kt*32 + q*8];
      accR[0]=MFMA(a0,Breg[kt][0],accR[0]);  accR[1]=MFMA(a0,Breg[kt][1],accR[1]);
      accZ[0]=MFMA(a0,Breg[kt][2],accZ[0]);  accZ[1]=MFMA(a0,Breg[kt][3],accZ[1]);
      accNH[0]=MFMA(a0,Breg[kt][4],accNH[0]); accNH[1]=MFMA(a0,Breg[kt][5],accNH[1]);
    }
    __syncthreads();
#pragma unroll
    for (int jt = 0; jt < 2; jt++)
#pragma unroll
    for (int rg = 0; rg < 4; rg++) {
      const float r = sigf(gr[jt] + bR[jt] + accR[jt][rg]);
      const float z = sigf(gz[jt] + bZ[jt] + accZ[jt][rg]);
      const float n = tanhf_(gn[jt] + bNX[jt] + r*(accNH[jt][rg] + bNH[jt]));
      float h = hst[jt][rg];
      h = (1.0f - z)*n + z*h;
      hst[jt][rg] = h;
      hbf[q*4 + rg][32*w + jt*16 + c] = tobf(h);
    }
    __syncthreads();
  }
  if (q == 0) {
#pragma unroll
    for (int jt = 0; jt < 2; jt++)
      doc[d*256 + 32*w + jt*16 + c] = hst[jt][0];
  }
}

// ---------------------------------------------------------------------------
// fp32 GEMM, BM=16/BN=64 (review-level gx, K=276)
// ---------------------------------------------------------------------------
__global__ __launch_bounds__(256) void gemm_nt16(
    const float* __restrict__ A, const float* __restrict__ B, float* __restrict__ C,
    int M, int N, int K)
{
  const int m0 = blockIdx.x * 16;
  const int n0 = blockIdx.y * 64;
  const int tid = threadIdx.x;
  __shared__ float As[16][17];
  __shared__ float Bs[16][68];
  float acc[4] = {0,0,0,0};
  const int m  = tid >> 4, n4 = (tid & 15) * 4;
  const int bn = tid >> 2, bk = (tid & 3) * 4;
  for (int k0 = 0; k0 < K; k0 += 16) {
    const int ak = tid & 15;
    float av = (k0 + ak < K) ? A[(size_t)(m0+m)*K + k0 + ak] : 0.0f;
    float4 b4 = make_float4(0,0,0,0);
    if (k0 + bk < K) b4 = *(const float4*)&B[(size_t)(n0+bn)*K + k0 + bk];
    __syncthreads();
    As[ak][m] = av;
    Bs[bk+0][bn]=b4.x; Bs[bk+1][bn]=b4.y; Bs[bk+2][bn]=b4.z; Bs[bk+3][bn]=b4.w;
    __syncthreads();
#pragma unroll
    for (int k = 0; k < 16; k++) {
      const float a = As[k][m];
      const float4 bb = *(const float4*)&Bs[k][n4];
      acc[0]+=a*bb.x; acc[1]+=a*bb.y; acc[2]+=a*bb.z; acc[3]+=a*bb.w;
    }
  }
  *(float4*)&C[(size_t)(m0+m)*N + n0+n4] = make_float4(acc[0],acc[1],acc[2],acc[3]);
}

// ---------------------------------------------------------------------------
// Small glue kernels
// ---------------------------------------------------------------------------
__global__ void pbatch_k(const float* __restrict__ hs, const float* __restrict__ uf,
                         const float* __restrict__ ufw, float* __restrict__ pb)
{
  const int r = blockIdx.x, tid = threadIdx.x;
  __shared__ float nrm;
  if (tid == 0) {
    float s = 0.f;
    for (int i = 0; i < UF_; i++) { const float v = uf[r*UF_ + i]; s += v*v; }
    nrm = fmaxf(sqrtf(s), 1e-12f);
  }
  __syncthreads();
  if (tid < H_)  pb[r*276 + tid] = hs[r*H_ + tid] + hs[(size_t)R_*H_ + r*H_ + tid];
  if (tid < UF_) pb[r*276 + H_ + tid] = uf[r*UF_ + tid] / nrm * ufw[tid];
}

__global__ void rstars_k(const float* __restrict__ pb,
                         const float* __restrict__ w1, const float* __restrict__ b1,
                         const float* __restrict__ w2, const float* __restrict__ b2,
                         float* __restrict__ out)
{
  const int r = blockIdx.x, tid = threadIdx.x;   // 128 threads
  __shared__ float ps[276];
  __shared__ float s1[128];
  for (int i = tid; i < 276; i += 128) ps[i] = pb[r*276 + i];
  __syncthreads();
  float a = b1[tid];
  for (int k = 0; k < 276; k++) a += ps[k] * w1[tid*276 + k];
  s1[tid] = seluf_(a);
  __syncthreads();
  if (tid == 0) {
    float s = b2[0];
    for (int k = 0; k < 128; k++) s += s1[k] * w2[k];
    out[9 + r] = s;
  }
}

__global__ void pstars_k(const float* __restrict__ doc2,
                         const float* __restrict__ w1, const float* __restrict__ b1,
                         const float* __restrict__ w2, const float* __restrict__ b2,
                         float* __restrict__ out)
{
  const int tid = threadIdx.x;   // 128 threads
  __shared__ float dc[256];
  __shared__ float s1[128];
  dc[tid]       = doc2[tid]       + doc2[256 + tid];
  dc[128 + tid] = doc2[128 + tid] + doc2[384 + tid];
  __syncthreads();
  float a = b1[tid];
  for (int k = 0; k < 256; k++) a += dc[k] * w1[tid*256 + k];
  s1[tid] = seluf_(a);
  __syncthreads();
  if (tid < 9) {
    float s = b2[tid];
    for (int k = 0; k < 128; k++) s += s1[k] * w2[tid*128 + k];
    out[tid] = s;
  }
}

// ---------------------------------------------------------------------------
extern "C" void kernel_launch(void* const* d_in, const int* in_sizes, int n_in,
                              void* d_out, int out_size, void* d_ws, size_t ws_size,
                              hipStream_t stream)
{
  const int*   toks   = (const int*)  d_in[0];
  const float* uf     = (const float*)d_in[3];
  const float* embed  = (const float*)d_in[4];
  const float* wg_wih = (const float*)d_in[5];
  const float* wg_whh = (const float*)d_in[6];
  const float* wg_bih = (const float*)d_in[7];
  const float* wg_bhh = (const float*)d_in[8];
  const float* sg_wih = (const float*)d_in[9];
  const float* sg_whh = (const float*)d_in[10];
  const float* sg_bih = (const float*)d_in[11];
  const float* sg_bhh = (const float*)d_in[12];
  const float* rg_wih = (const float*)d_in[13];
  const float* rg_whh = (const float*)d_in[14];
  const float* rg_bih = (const float*)d_in[15];
  const float* rg_bhh = (const float*)d_in[16];
  const float* rfc_w1 = (const float*)d_in[17];
  const float* rfc_b1 = (const float*)d_in[18];
  const float* rfc_w2 = (const float*)d_in[19];
  const float* rfc_b2 = (const float*)d_in[20];
  const float* pfc_w1 = (const float*)d_in[21];
  const float* pfc_b1 = (const float*)d_in[22];
  const float* pfc_w2 = (const float*)d_in[23];
  const float* pfc_b2 = (const float*)d_in[24];
  const float* uf_w   = (const float*)d_in[25];
  float* out = (float*)d_out;
  float* ws  = (float*)d_ws;
  (void)in_sizes; (void)n_in; (void)out_size;

  // workspace layout (float offsets)
  const size_t OFF_BW   = 0;                         // 393,216
  const size_t OFF_BS   = OFF_BW  + 393216;          // 196,608
  const size_t OFF_BR   = OFF_BS  + 196608;          // 196,608
  const size_t OFF_BG   = OFF_BR  + 196608;          // 196,608
  const size_t OFF_BGW  = OFF_BG  + 196608;          // 196,608
  const size_t OFF_HF   = OFF_BGW + 196608;          // 1,048,576
  const size_t OFF_SB   = OFF_HF  + 1048576;         // 262,144
  const size_t OFF_GXS  = OFF_SB  + 262144;          // 1,572,864 (bf16 2048x1536)
  const size_t OFF_HS   = OFF_GXS + 1572864;         // 32,768
  const size_t OFF_PB   = OFF_HS  + 32768;           // 17,664
  const size_t OFF_GXR  = OFF_PB  + 17664;           // 98,304
  const size_t OFF_DOC  = OFF_GXR + 98304;           // 512
  const size_t OFF_GXT  = OFF_DOC + 512;             // B: 2x 8192x768 bf16 = 6,291,456 f
  const size_t TOT_A    = OFF_GXT + (size_t)50048*1536/2;   // gxv bf16

  short* Bw   = (short*)(ws + OFF_BW);
  short* Bs   = (short*)(ws + OFF_BS);
  short* Br   = (short*)(ws + OFF_BR);
  short* Bg   = (short*)(ws + OFF_BG);
  short* Bgw  = (short*)(ws + OFF_BGW);
  float* hfin = ws + OFF_HF;
  short* sentb= (short*)(ws + OFF_SB);
  short* gxs  = (short*)(ws + OFF_GXS);
  float* hs   = ws + OFF_HS;
  float* pb   = ws + OFF_PB;
  float* gxr  = ws + OFF_GXR;
  float* doc  = ws + OFF_DOC;
  short* gxf  = (short*)(ws + OFF_GXT);
  short* gxb  = gxf + (size_t)8192*768;
  short* gxv  = (short*)(ws + OFF_GXT);

  const bool big = ws_size >= TOT_A * sizeof(float);

  prep_word_w<<<384, 256, 0, stream>>>(wg_wih, wg_whh, Bw);
  prep_rnn_w<<<192, 256, 0, stream>>>(sg_whh, Bs);
  prep_rnn_w<<<192, 256, 0, stream>>>(rg_whh, Br);
  prep_gemm_w<<<192, 256, 0, stream>>>(sg_wih, Bg);
  prep_gemm_w<<<192, 256, 0, stream>>>(wg_wih, Bgw);

  if (big) {
    // path A: per-vocab x-gates (bf16), single recurrence launch
    gemm_gxu<<<dim3(782, 12, 1), 256, 0, stream>>>(
        nullptr, embed, nullptr, Bgw, gxv, 0, 1, 0, 50000, 1536);
    gru_rec<<<256, 512, 0, stream>>>(toks, gxv, nullptr, Bw, 49152, 8,
        wg_bih, wg_bhh, hfin, 2048, 0, 64, 0, 64);
  } else {
    // path B: time-chunked x-gate GEMM + 4-step recurrence, 16 rounds
    for (int tc = 0; tc < 64/TC; tc++) {
      gemm_gxu<<<dim3(128, 6, 2), 256, 0, stream>>>(
          nullptr, embed, toks, Bgw, gxf, (long)8192*768, 2, tc*TC, 0, 768);
      gru_rec<<<256, 512, 0, stream>>>(toks, gxf, gxb, Bw, 49152, 8,
          wg_bih, wg_bhh, hfin, 2048, tc*TC, TC, 1, 64);
    }
  }
  add2bf<<<512, 256, 0, stream>>>(hfin, hfin + (size_t)2048*256, sentb);

  // sentence level: gx GEMM (bf16 out) + recurrence (weights in regs)
  gemm_gxu<<<dim3(32, 12, 1), 256, 0, stream>>>(
      sentb, nullptr, nullptr, Bg, gxs, 0, 0, 0, 2048, 1536);
  gru_rec<<<8, 512, 0, stream>>>(nullptr, gxs, nullptr, Bs, 24576, 0,
      sg_bih, sg_bhh, hs, 64, 0, 32, 2, 32);

  // p_batch + r_stars
  pbatch_k<<<R_, 256, 0, stream>>>(hs, uf, uf_w, pb);
  rstars_k<<<R_, 128, 0, stream>>>(pb, rfc_w1, rfc_b1, rfc_w2, rfc_b2, out);

  // review level: fp32 gx GEMM + persistent bi-GRU + p_stars
  gemm_nt16<<<dim3(4, 24), 256, 0, stream>>>(pb, rg_wih, gxr, 64, 1536, 276);
  rev_gru<<<2, 512, 0, stream>>>(gxr, Br, rg_bih, rg_bhh, doc);
  pstars_k<<<1, 128, 0, stream>>>(doc, pfc_w1, pfc_b1, pfc_w2, pfc_b2, out);
}